// Round 7
// baseline (211.300 us; speedup 1.0000x reference)
//
#include <hip/hip_runtime.h>
#include <hip/hip_bf16.h>
#include <cstdint>

#define DIMC 1024
#define HEADS 16
#define DHH 64
#define SEQ 4096
#define LATENT 1024
#define HISTC 3072
#define BATCH 2

typedef __attribute__((ext_vector_type(8))) __bf16 bf16x8;
typedef __attribute__((ext_vector_type(4))) float f32x4;
typedef __attribute__((ext_vector_type(16))) float f32x16;

// ---------------- fp32 -> bf16 convert (vectorized) ----------------
__global__ void k_convert(const float* __restrict__ in, __bf16* __restrict__ out, int n) {
  int stride = gridDim.x * blockDim.x;
  int nc = n >> 2;
  for (int i = blockIdx.x * blockDim.x + threadIdx.x; i < nc; i += stride) {
    float4 v = reinterpret_cast<const float4*>(in)[i];
    union { __bf16 h[4]; uint64_t u; } p;
    p.h[0] = (__bf16)v.x; p.h[1] = (__bf16)v.y;
    p.h[2] = (__bf16)v.z; p.h[3] = (__bf16)v.w;
    reinterpret_cast<uint64_t*>(out)[i] = p.u;
  }
}

// three weight matrices (1024x1024 each) in one launch
__global__ void k_convert3(const float* __restrict__ a, const float* __restrict__ b,
                           const float* __restrict__ c, __bf16* __restrict__ oa,
                           __bf16* __restrict__ ob, __bf16* __restrict__ oc) {
  int id = blockIdx.x;
  const float* src; __bf16* dst;
  if (id < 512) { src = a; dst = oa; }
  else if (id < 1024) { src = b; dst = ob; id -= 512; }
  else { src = c; dst = oc; id -= 1024; }
#pragma unroll
  for (int k = 0; k < 2; ++k) {
    int idx = id * 512 + k * 256 + threadIdx.x;
    float4 v = reinterpret_cast<const float4*>(src)[idx];
    union { __bf16 h[4]; uint64_t u; } p;
    p.h[0] = (__bf16)v.x; p.h[1] = (__bf16)v.y;
    p.h[2] = (__bf16)v.z; p.h[3] = (__bf16)v.w;
    reinterpret_cast<uint64_t*>(dst)[idx] = p.u;
  }
}

// ---------------- async global->LDS 16B ----------------
__device__ __forceinline__ void gload16(void* lds, const void* g) {
  __builtin_amdgcn_global_load_lds(
      (const __attribute__((address_space(1))) unsigned int*)g,
      (__attribute__((address_space(3))) unsigned int*)lds, 16, 0, 0);
}

// ---------------- plain GEMM (used for o-proj): C = A @ Bw^T + bias ----
template<int QREMAP, int BIAS>
__launch_bounds__(256)
__global__ void k_gemm(const __bf16* __restrict__ A, const __bf16* __restrict__ Bw,
                       float* __restrict__ C, const float* __restrict__ bias,
                       int M, int N, int K) {
  __shared__ __align__(16) char lds[16384];
  const int t = threadIdx.x;
  const int l = t & 63, w = t >> 6;
  const int wr = w >> 1, wc = w & 1;
  const int m0 = blockIdx.y * 128, n0 = blockIdx.x * 128;
  const int lrow = l & 15, lk = l >> 4;
  f32x4 acc[4][4] = {};

  for (int k0 = 0; k0 < K; k0 += 32) {
    if (k0) __syncthreads();
#pragma unroll
    for (int i = 0; i < 2; ++i) {
      int c = i * 256 + t;
      int row = c >> 2, kc = c & 3;
      int mi = m0 + row;
      if (QREMAP) mi += HISTC + (mi >> 10) * HISTC;
      gload16(lds + c * 16, A + (size_t)mi * K + k0 + kc * 8);
      gload16(lds + 8192 + c * 16, Bw + (size_t)(n0 + row) * K + k0 + kc * 8);
    }
    __syncthreads();
    bf16x8 af[4], bfr[4];
#pragma unroll
    for (int m = 0; m < 4; ++m)
      af[m] = *reinterpret_cast<const bf16x8*>(lds + (wr * 64 + m * 16 + lrow) * 64 + lk * 16);
#pragma unroll
    for (int n = 0; n < 4; ++n)
      bfr[n] = *reinterpret_cast<const bf16x8*>(lds + 8192 + (wc * 64 + n * 16 + lrow) * 64 + lk * 16);
#pragma unroll
    for (int m = 0; m < 4; ++m)
#pragma unroll
      for (int n = 0; n < 4; ++n)
        acc[m][n] = __builtin_amdgcn_mfma_f32_16x16x32_bf16(af[m], bfr[n], acc[m][n], 0, 0, 0);
  }

#pragma unroll
  for (int m = 0; m < 4; ++m)
#pragma unroll
    for (int n = 0; n < 4; ++n)
#pragma unroll
      for (int r = 0; r < 4; ++r) {
        int row = m0 + wr * 64 + m * 16 + (l >> 4) * 4 + r;
        int col = n0 + wc * 64 + n * 16 + (l & 15);
        float v = acc[m][n][r];
        if (BIAS) v += bias[col];
        C[(size_t)row * N + col] = v;
      }
}

// ---------------- fused QKV GEMM: kv-proj(+RoPE+LN) and q-proj(+RoPE+scale) ----
__launch_bounds__(256)
__global__ void k_gemmqkv(const __bf16* __restrict__ x16,
                          const __bf16* __restrict__ wkv16,
                          const __bf16* __restrict__ wq16,
                          __bf16* __restrict__ kvn, __bf16* __restrict__ kvnT,
                          __bf16* __restrict__ qb,
                          const float* __restrict__ gamma,
                          const float* __restrict__ beta) {
  __shared__ __align__(16) char lds[16384];
  const int t = threadIdx.x, l = t & 63, w = t >> 6;
  const int wr = w >> 1, wc = w & 1;
  const int by = blockIdx.y;
  const bool isq = by >= 64;
  const int m0 = (isq ? (by - 64) : by) * 128;
  const int n0 = blockIdx.x * 128;
  const __bf16* Bw = isq ? wq16 : wkv16;
  const int lrow = l & 15, lk = l >> 4;
  f32x4 acc[4][4] = {};

  for (int k0 = 0; k0 < 1024; k0 += 32) {
    if (k0) __syncthreads();
#pragma unroll
    for (int i = 0; i < 2; ++i) {
      int c = i * 256 + t;
      int row = c >> 2, kc = c & 3;
      int mi = m0 + row;
      if (isq) mi += HISTC + (mi >> 10) * HISTC;
      gload16(lds + c * 16, x16 + (size_t)mi * 1024 + k0 + kc * 8);
      gload16(lds + 8192 + c * 16, Bw + (size_t)(n0 + row) * 1024 + k0 + kc * 8);
    }
    __syncthreads();
    bf16x8 af[4], bfr[4];
#pragma unroll
    for (int m = 0; m < 4; ++m)
      af[m] = *reinterpret_cast<const bf16x8*>(lds + (wr * 64 + m * 16 + lrow) * 64 + lk * 16);
#pragma unroll
    for (int n = 0; n < 4; ++n)
      bfr[n] = *reinterpret_cast<const bf16x8*>(lds + 8192 + (wc * 64 + n * 16 + lrow) * 64 + lk * 16);
#pragma unroll
    for (int m = 0; m < 4; ++m)
#pragma unroll
      for (int n = 0; n < 4; ++n)
        acc[m][n] = __builtin_amdgcn_mfma_f32_16x16x32_bf16(af[m], bfr[n], acc[m][n], 0, 0, 0);
  }

  // ---- RoPE in place (pairs (0,2) and (1,3) share one lane) ----
  const float LG = 0.41524101186f;               // log2(10000)/32
  float invf0 = exp2f(-(float)lrow * LG);
  float invf1 = exp2f(-(float)(lrow + 16) * LG);
#pragma unroll
  for (int m = 0; m < 4; ++m)
#pragma unroll
    for (int r = 0; r < 4; ++r) {
      int rl = wr * 64 + m * 16 + lk * 4 + r;
      int pos = isq ? (HISTC + ((m0 + rl) & 1023)) : ((m0 + rl) & 4095);
      float fp = (float)pos;
      float s0, c0, s1, c1;
      sincosf(fp * invf0, &s0, &c0);
      sincosf(fp * invf1, &s1, &c1);
      float a0 = acc[m][0][r], a2 = acc[m][2][r];
      acc[m][0][r] = a0 * c0 - a2 * s0;
      acc[m][2][r] = a2 * c0 + a0 * s0;
      float a1 = acc[m][1][r], a3 = acc[m][3][r];
      acc[m][1][r] = a1 * c1 - a3 * s1;
      acc[m][3][r] = a3 * c1 + a1 * s1;
    }

  const int h = (n0 + wc * 64) >> 6;
  if (!isq) {
    // ---- per-head LayerNorm over the 64 cols (16-lane reduction) ----
    float g4[4], b4[4];
#pragma unroll
    for (int n = 0; n < 4; ++n) { g4[n] = gamma[n * 16 + lrow]; b4[n] = beta[n * 16 + lrow]; }
#pragma unroll
    for (int m = 0; m < 4; ++m)
#pragma unroll
      for (int r = 0; r < 4; ++r) {
        float s1 = acc[m][0][r] + acc[m][1][r] + acc[m][2][r] + acc[m][3][r];
        float s2 = acc[m][0][r] * acc[m][0][r] + acc[m][1][r] * acc[m][1][r] +
                   acc[m][2][r] * acc[m][2][r] + acc[m][3][r] * acc[m][3][r];
#pragma unroll
        for (int mk = 1; mk < 16; mk <<= 1) {
          s1 += __shfl_xor(s1, mk);
          s2 += __shfl_xor(s2, mk);
        }
        float mu = s1 * 0.015625f;
        float var = s2 * 0.015625f - mu * mu;
        float inv = rsqrtf(var + 1e-5f);
#pragma unroll
        for (int n = 0; n < 4; ++n)
          acc[m][n][r] = (acc[m][n][r] - mu) * inv * g4[n] + b4[n];
      }
    const size_t hb = (size_t)((m0 >> 12) * HEADS + h);
    // kvn [b,h,pos,d]
#pragma unroll
    for (int m = 0; m < 4; ++m)
#pragma unroll
      for (int r = 0; r < 4; ++r) {
        int pos = (m0 + wr * 64 + m * 16 + lk * 4 + r) & 4095;
#pragma unroll
        for (int n = 0; n < 4; ++n)
          kvn[(hb * SEQ + pos) * DHH + n * 16 + lrow] = (__bf16)acc[m][n][r];
      }
    // kvnT [b,h,d,sigma(pos)] : r-quads stay contiguous under sigma (bits 2,3 swap)
#pragma unroll
    for (int m = 0; m < 4; ++m) {
      int pos0 = (m0 + wr * 64 + m * 16 + lk * 4) & 4095;
      int sp = (pos0 & ~12) | ((pos0 & 4) << 1) | ((pos0 & 8) >> 1);
#pragma unroll
      for (int n = 0; n < 4; ++n) {
        union { __bf16 hh[4]; uint64_t u; } pk;
#pragma unroll
        for (int r = 0; r < 4; ++r) pk.hh[r] = (__bf16)acc[m][n][r];
        *reinterpret_cast<uint64_t*>(kvnT + (hb * DHH + n * 16 + lrow) * SEQ + sp) = pk.u;
      }
    }
  } else {
    // ---- q: scale by DH^-0.5 * log2(e), write qb [b,h,i,d] ----
    const size_t hb = (size_t)((m0 >> 10) * HEADS + h);
#pragma unroll
    for (int m = 0; m < 4; ++m)
#pragma unroll
      for (int r = 0; r < 4; ++r) {
        int qi = (m0 + wr * 64 + m * 16 + lk * 4 + r) & 1023;
#pragma unroll
        for (int n = 0; n < 4; ++n)
          qb[(hb * LATENT + qi) * DHH + n * 16 + lrow] =
              (__bf16)(acc[m][n][r] * 0.18033688011112042f);
      }
  }
}

// ---------------- helpers for flash ----------------
__device__ __forceinline__ float fexp2(float x) {
#if __has_builtin(__builtin_amdgcn_exp2f)
  return __builtin_amdgcn_exp2f(x);
#else
  return exp2f(x);
#endif
}

__device__ __forceinline__ unsigned pk2(float a, float b) {
  union { __bf16 h[2]; unsigned u; } x;
  x.h[0] = (__bf16)a; x.h[1] = (__bf16)b;
  return x.u;
}

// ---------------- flash attention v6 ----------------
// XCD-pinned, swapped QK^T, sigma-permuted kvnT. NO LDS in the main loop:
// V^T loaded directly into MFMA A-frags (L2-resident after XCD pinning;
// issued at top of iter so QK+softmax hide the latency). K prefetched one
// tile ahead. LDS used only for the final 4-wave merge. setprio around MFMAs.
__launch_bounds__(256)
__global__ void k_flash6(const __bf16* __restrict__ qb, const __bf16* __restrict__ kvn,
                         const __bf16* __restrict__ kvnT, __bf16* __restrict__ aout) {
  const int bid = blockIdx.x;
  const int bh = (bid & 7) + 8 * (bid >> 8);
  const int itile = (bid >> 3) & 31;
  const int h = bh & 15, b = bh >> 4;
  const int t = threadIdx.x, l = t & 63, w = t >> 6;
  const int q = l & 31, hi = l >> 5;
  const int iw = itile * 32;
  const int i = iw + q;
  const __bf16* qbase = qb + ((size_t)(b * HEADS + h) * LATENT + iw) * DHH;
  const __bf16* kbase = kvn + (size_t)(b * HEADS + h) * SEQ * DHH;
  const __bf16* vbase = kvnT + (size_t)(b * HEADS + h) * DHH * SEQ;

  __shared__ __align__(16) char smem[4][4352];   // per-wave O merge [32][33]f32 (+pad)
  __shared__ float Mlds[4][32];
  __shared__ float Llds[4][32];

  bf16x8 qf[4];
#pragma unroll
  for (int c = 0; c < 4; ++c)
    qf[c] = *reinterpret_cast<const bf16x8*>(qbase + (size_t)q * DHH + c * 16 + hi * 8);

  const f32x16 Z = {};
  f32x16 O0 = {}, O1 = {};
  float m_run = -INFINITY, lacc = 0.f;

  const int nt = itile + 97;
  const int t0 = (nt * w) >> 2, t1 = (nt * (w + 1)) >> 2;

  // per-lane row bases
  const __bf16* kptr = kbase + (size_t)q * DHH + hi * 8;          // row j0+q via +j0*DHH
  const __bf16* vrow0 = vbase + (size_t)q * SEQ + hi * 8;         // d = q
  const __bf16* vrow1 = vbase + (size_t)(32 + q) * SEQ + hi * 8;  // d = 32+q

  bf16x8 kreg[4];
#pragma unroll
  for (int c = 0; c < 4; ++c)
    kreg[c] = *reinterpret_cast<const bf16x8*>(kptr + (size_t)t0 * 32 * DHH + c * 16);

  for (int tt = t0; tt < t1; ++tt) {
    const int j0 = tt * 32;
    // V A-frags for THIS tile, issued first: QK+softmax hides their latency
    bf16x8 va00 = *reinterpret_cast<const bf16x8*>(vrow0 + j0);
    bf16x8 va01 = *reinterpret_cast<const bf16x8*>(vrow0 + j0 + 16);
    bf16x8 va10 = *reinterpret_cast<const bf16x8*>(vrow1 + j0);
    bf16x8 va11 = *reinterpret_cast<const bf16x8*>(vrow1 + j0 + 16);
    // QK^T swapped: S[key][qrow]
    __builtin_amdgcn_s_setprio(1);
    f32x16 S = __builtin_amdgcn_mfma_f32_32x32x16_bf16(kreg[0], qf[0], Z, 0, 0, 0);
    S = __builtin_amdgcn_mfma_f32_32x32x16_bf16(kreg[1], qf[1], S, 0, 0, 0);
    S = __builtin_amdgcn_mfma_f32_32x32x16_bf16(kreg[2], qf[2], S, 0, 0, 0);
    S = __builtin_amdgcn_mfma_f32_32x32x16_bf16(kreg[3], qf[3], S, 0, 0, 0);
    __builtin_amdgcn_s_setprio(0);
    // prefetch K(tt+1) (clamped; SSA renaming -> no copies, full-iter distance)
    {
      const size_t jn = (size_t)((tt + 1 < t1) ? tt + 1 : tt) * 32 * DHH;
#pragma unroll
      for (int c = 0; c < 4; ++c)
        kreg[c] = *reinterpret_cast<const bf16x8*>(kptr + jn + c * 16);
    }
    // mask: j - HIST > i
    if (j0 + 31 > iw + HISTC) {
#pragma unroll
      for (int r = 0; r < 16; ++r) {
        int j = j0 + (r & 3) + 8 * (r >> 2) + 4 * hi;
        if (j > i + HISTC) S[r] = -1e30f;
      }
    }
    // lane-local max (max3-friendly tree)
    float u1 = fmaxf(fmaxf(S[0], S[1]), S[2]);
    float u2 = fmaxf(fmaxf(S[3], S[4]), S[5]);
    float u3 = fmaxf(fmaxf(S[6], S[7]), S[8]);
    float u4 = fmaxf(fmaxf(S[9], S[10]), S[11]);
    float u5 = fmaxf(fmaxf(S[12], S[13]), S[14]);
    float pm = fmaxf(fmaxf(fmaxf(u1, u2), u3), fmaxf(fmaxf(u4, u5), S[15]));
    // defer-max: rescale (and sync halves' max) only when needed
    if (__any(pm > m_run + 8.0f)) {
      pm = fmaxf(pm, __shfl_xor(pm, 32));
      float mn = fmaxf(m_run, pm);
      float sc = fexp2(m_run - mn);          // first tile: exp2(-inf)=0
      m_run = mn;
      lacc *= sc;
#pragma unroll
      for (int r = 0; r < 16; ++r) { O0[r] *= sc; O1[r] *= sc; }
    }
    // P = 2^(S-m); lane-local sum
    float p[16];
#pragma unroll
    for (int r = 0; r < 16; ++r) p[r] = fexp2(S[r] - m_run);
    float s8[8];
#pragma unroll
    for (int r = 0; r < 8; ++r) s8[r] = p[r] + p[r + 8];
    float s4_0 = s8[0] + s8[4], s4_1 = s8[1] + s8[5];
    float s4_2 = s8[2] + s8[6], s4_3 = s8[3] + s8[7];
    lacc += (s4_0 + s4_1) + (s4_2 + s4_3);
    // PV B-frags = own p's (sigma-permuted V absorbs the exchange)
    union { unsigned u[4]; bf16x8 v; } pf0, pf1;
    pf0.u[0] = pk2(p[0], p[1]);   pf0.u[1] = pk2(p[2], p[3]);
    pf0.u[2] = pk2(p[4], p[5]);   pf0.u[3] = pk2(p[6], p[7]);
    pf1.u[0] = pk2(p[8], p[9]);   pf1.u[1] = pk2(p[10], p[11]);
    pf1.u[2] = pk2(p[12], p[13]); pf1.u[3] = pk2(p[14], p[15]);
    // PV
    __builtin_amdgcn_s_setprio(1);
    O0 = __builtin_amdgcn_mfma_f32_32x32x16_bf16(va00, pf0.v, O0, 0, 0, 0);
    O0 = __builtin_amdgcn_mfma_f32_32x32x16_bf16(va01, pf1.v, O0, 0, 0, 0);
    O1 = __builtin_amdgcn_mfma_f32_32x32x16_bf16(va10, pf0.v, O1, 0, 0, 0);
    O1 = __builtin_amdgcn_mfma_f32_32x32x16_bf16(va11, pf1.v, O1, 0, 0, 0);
    __builtin_amdgcn_s_setprio(0);
  }
  float l_run = lacc + __shfl_xor(lacc, 32);

  // -------- merge the 4 waves' partial (O, m, l), chunked over d --------
  float (*Ow)[33] = reinterpret_cast<float(*)[33]>(smem[w]);
  if (hi == 0) { Mlds[w][q] = m_run; Llds[w][q] = l_run; }
#pragma unroll
  for (int r = 0; r < 16; ++r)
    Ow[q][(r & 3) + 8 * (r >> 2) + 4 * hi] = O0[r];
  __syncthreads();
  const int mi = t >> 3, dl = (t & 7) * 4;
  float m0v = Mlds[0][mi], m1v = Mlds[1][mi], m2v = Mlds[2][mi], m3v = Mlds[3][mi];
  float mm = fmaxf(fmaxf(m0v, m1v), fmaxf(m2v, m3v));
  float sc0 = fexp2(m0v - mm), sc1 = fexp2(m1v - mm);
  float sc2 = fexp2(m2v - mm), sc3 = fexp2(m3v - mm);
  float ll = Llds[0][mi] * sc0 + Llds[1][mi] * sc1 + Llds[2][mi] * sc2 + Llds[3][mi] * sc3;
  float inv = 1.f / ll;
  __bf16* orow = aout + ((size_t)(b * LATENT) + iw + mi) * DIMC + h * DHH;
  {
    float(*O0p)[33] = reinterpret_cast<float(*)[33]>(smem[0]);
    float(*O1p)[33] = reinterpret_cast<float(*)[33]>(smem[1]);
    float(*O2p)[33] = reinterpret_cast<float(*)[33]>(smem[2]);
    float(*O3p)[33] = reinterpret_cast<float(*)[33]>(smem[3]);
    union { __bf16 hh[4]; uint2 u2; } pkv;
#pragma unroll
    for (int e = 0; e < 4; ++e) {
      float o = O0p[mi][dl + e] * sc0 + O1p[mi][dl + e] * sc1 +
                O2p[mi][dl + e] * sc2 + O3p[mi][dl + e] * sc3;
      pkv.hh[e] = (__bf16)(o * inv);
    }
    *reinterpret_cast<uint2*>(orow + dl) = pkv.u2;
  }
  __syncthreads();
#pragma unroll
  for (int r = 0; r < 16; ++r)
    Ow[q][(r & 3) + 8 * (r >> 2) + 4 * hi] = O1[r];
  __syncthreads();
  {
    float(*O0p)[33] = reinterpret_cast<float(*)[33]>(smem[0]);
    float(*O1p)[33] = reinterpret_cast<float(*)[33]>(smem[1]);
    float(*O2p)[33] = reinterpret_cast<float(*)[33]>(smem[2]);
    float(*O3p)[33] = reinterpret_cast<float(*)[33]>(smem[3]);
    union { __bf16 hh[4]; uint2 u2; } pkv;
#pragma unroll
    for (int e = 0; e < 4; ++e) {
      float o = O0p[mi][dl + e] * sc0 + O1p[mi][dl + e] * sc1 +
                O2p[mi][dl + e] * sc2 + O3p[mi][dl + e] * sc3;
      pkv.hh[e] = (__bf16)(o * inv);
    }
    *reinterpret_cast<uint2*>(orow + 32 + dl) = pkv.u2;
  }
}

// ---------------- host launcher ----------------
extern "C" void kernel_launch(void* const* d_in, const int* in_sizes, int n_in,
                              void* d_out, int out_size, void* d_ws, size_t ws_size,
                              hipStream_t stream) {
  const float* x = (const float*)d_in[0];
  const float* Wq = (const float*)d_in[1];
  const float* Wkv = (const float*)d_in[2];
  const float* Wo = (const float*)d_in[3];
  const float* bo = (const float*)d_in[4];
  const float* gamma = (const float*)d_in[5];
  const float* beta = (const float*)d_in[6];

  char* ws = (char*)d_ws;
  size_t o = 0;
  __bf16* x16 = (__bf16*)(ws + o);  o += (size_t)BATCH * SEQ * DIMC * 2;
  __bf16* wq16 = (__bf16*)(ws + o); o += (size_t)DIMC * DIMC * 2;
  __bf16* wkv16 = (__bf16*)(ws + o); o += (size_t)DIMC * DIMC * 2;
  __bf16* wo16 = (__bf16*)(ws + o); o += (size_t)DIMC * DIMC * 2;
  __bf16* kvn = (__bf16*)(ws + o);  o += (size_t)BATCH * HEADS * SEQ * DHH * 2;
  __bf16* kvnT = (__bf16*)(ws + o); o += (size_t)BATCH * HEADS * SEQ * DHH * 2;
  __bf16* qb = (__bf16*)(ws + o);   o += (size_t)BATCH * HEADS * LATENT * DHH * 2;
  __bf16* aout = (__bf16*)(ws + o); o += (size_t)BATCH * LATENT * DIMC * 2;

  k_convert<<<2048, 256, 0, stream>>>(x, x16, BATCH * SEQ * DIMC);
  k_convert3<<<1536, 256, 0, stream>>>(Wq, Wkv, Wo, wq16, wkv16, wo16);
  k_gemmqkv<<<dim3(8, 80), 256, 0, stream>>>(x16, wkv16, wq16, kvn, kvnT, qb, gamma, beta);
  k_flash6<<<1024, 256, 0, stream>>>(qb, kvn, kvnT, aout);
  k_gemm<0, 1><<<dim3(8, 16), 256, 0, stream>>>(aout, wo16, (float*)d_out, bo, 2048, 1024, 1024);
}

// Round 8
// 174.149 us; speedup vs baseline: 1.2133x; 1.2133x over previous
//
#include <hip/hip_runtime.h>
#include <hip/hip_bf16.h>
#include <cstdint>

#define DIMC 1024
#define HEADS 16
#define DHH 64
#define SEQ 4096
#define LATENT 1024
#define HISTC 3072
#define BATCH 2

typedef __attribute__((ext_vector_type(8))) __bf16 bf16x8;
typedef __attribute__((ext_vector_type(4))) float f32x4;
typedef __attribute__((ext_vector_type(16))) float f32x16;

// ---------------- fp32 -> bf16 convert (vectorized) ----------------
__global__ void k_convert(const float* __restrict__ in, __bf16* __restrict__ out, int n) {
  int stride = gridDim.x * blockDim.x;
  int nc = n >> 2;
  for (int i = blockIdx.x * blockDim.x + threadIdx.x; i < nc; i += stride) {
    float4 v = reinterpret_cast<const float4*>(in)[i];
    union { __bf16 h[4]; uint64_t u; } p;
    p.h[0] = (__bf16)v.x; p.h[1] = (__bf16)v.y;
    p.h[2] = (__bf16)v.z; p.h[3] = (__bf16)v.w;
    reinterpret_cast<uint64_t*>(out)[i] = p.u;
  }
}

// three weight matrices (1024x1024 each) in one launch
__global__ void k_convert3(const float* __restrict__ a, const float* __restrict__ b,
                           const float* __restrict__ c, __bf16* __restrict__ oa,
                           __bf16* __restrict__ ob, __bf16* __restrict__ oc) {
  int id = blockIdx.x;
  const float* src; __bf16* dst;
  if (id < 512) { src = a; dst = oa; }
  else if (id < 1024) { src = b; dst = ob; id -= 512; }
  else { src = c; dst = oc; id -= 1024; }
#pragma unroll
  for (int k = 0; k < 2; ++k) {
    int idx = id * 512 + k * 256 + threadIdx.x;
    float4 v = reinterpret_cast<const float4*>(src)[idx];
    union { __bf16 h[4]; uint64_t u; } p;
    p.h[0] = (__bf16)v.x; p.h[1] = (__bf16)v.y;
    p.h[2] = (__bf16)v.z; p.h[3] = (__bf16)v.w;
    reinterpret_cast<uint64_t*>(dst)[idx] = p.u;
  }
}

// ---------------- async global->LDS 16B ----------------
__device__ __forceinline__ void gload16(void* lds, const void* g) {
  __builtin_amdgcn_global_load_lds(
      (const __attribute__((address_space(1))) unsigned int*)g,
      (__attribute__((address_space(3))) unsigned int*)lds, 16, 0, 0);
}

// ---------------- plain GEMM (used for o-proj): C = A @ Bw^T + bias ----
template<int QREMAP, int BIAS>
__launch_bounds__(256)
__global__ void k_gemm(const __bf16* __restrict__ A, const __bf16* __restrict__ Bw,
                       float* __restrict__ C, const float* __restrict__ bias,
                       int M, int N, int K) {
  __shared__ __align__(16) char lds[16384];
  const int t = threadIdx.x;
  const int l = t & 63, w = t >> 6;
  const int wr = w >> 1, wc = w & 1;
  const int m0 = blockIdx.y * 128, n0 = blockIdx.x * 128;
  const int lrow = l & 15, lk = l >> 4;
  f32x4 acc[4][4] = {};

  for (int k0 = 0; k0 < K; k0 += 32) {
    if (k0) __syncthreads();
#pragma unroll
    for (int i = 0; i < 2; ++i) {
      int c = i * 256 + t;
      int row = c >> 2, kc = c & 3;
      int mi = m0 + row;
      if (QREMAP) mi += HISTC + (mi >> 10) * HISTC;
      gload16(lds + c * 16, A + (size_t)mi * K + k0 + kc * 8);
      gload16(lds + 8192 + c * 16, Bw + (size_t)(n0 + row) * K + k0 + kc * 8);
    }
    __syncthreads();
    bf16x8 af[4], bfr[4];
#pragma unroll
    for (int m = 0; m < 4; ++m)
      af[m] = *reinterpret_cast<const bf16x8*>(lds + (wr * 64 + m * 16 + lrow) * 64 + lk * 16);
#pragma unroll
    for (int n = 0; n < 4; ++n)
      bfr[n] = *reinterpret_cast<const bf16x8*>(lds + 8192 + (wc * 64 + n * 16 + lrow) * 64 + lk * 16);
#pragma unroll
    for (int m = 0; m < 4; ++m)
#pragma unroll
      for (int n = 0; n < 4; ++n)
        acc[m][n] = __builtin_amdgcn_mfma_f32_16x16x32_bf16(af[m], bfr[n], acc[m][n], 0, 0, 0);
  }

#pragma unroll
  for (int m = 0; m < 4; ++m)
#pragma unroll
    for (int n = 0; n < 4; ++n)
#pragma unroll
      for (int r = 0; r < 4; ++r) {
        int row = m0 + wr * 64 + m * 16 + (l >> 4) * 4 + r;
        int col = n0 + wc * 64 + n * 16 + (l & 15);
        float v = acc[m][n][r];
        if (BIAS) v += bias[col];
        C[(size_t)row * N + col] = v;
      }
}

// ---------------- fused QKV GEMM: kv-proj(+RoPE+LN) and q-proj(+RoPE+scale) ----
__launch_bounds__(256)
__global__ void k_gemmqkv(const __bf16* __restrict__ x16,
                          const __bf16* __restrict__ wkv16,
                          const __bf16* __restrict__ wq16,
                          __bf16* __restrict__ kvn, __bf16* __restrict__ kvnT,
                          __bf16* __restrict__ qb,
                          const float* __restrict__ gamma,
                          const float* __restrict__ beta) {
  __shared__ __align__(16) char lds[16384];
  const int t = threadIdx.x, l = t & 63, w = t >> 6;
  const int wr = w >> 1, wc = w & 1;
  const int by = blockIdx.y;
  const bool isq = by >= 64;
  const int m0 = (isq ? (by - 64) : by) * 128;
  const int n0 = blockIdx.x * 128;
  const __bf16* Bw = isq ? wq16 : wkv16;
  const int lrow = l & 15, lk = l >> 4;
  f32x4 acc[4][4] = {};

  for (int k0 = 0; k0 < 1024; k0 += 32) {
    if (k0) __syncthreads();
#pragma unroll
    for (int i = 0; i < 2; ++i) {
      int c = i * 256 + t;
      int row = c >> 2, kc = c & 3;
      int mi = m0 + row;
      if (isq) mi += HISTC + (mi >> 10) * HISTC;
      gload16(lds + c * 16, x16 + (size_t)mi * 1024 + k0 + kc * 8);
      gload16(lds + 8192 + c * 16, Bw + (size_t)(n0 + row) * 1024 + k0 + kc * 8);
    }
    __syncthreads();
    bf16x8 af[4], bfr[4];
#pragma unroll
    for (int m = 0; m < 4; ++m)
      af[m] = *reinterpret_cast<const bf16x8*>(lds + (wr * 64 + m * 16 + lrow) * 64 + lk * 16);
#pragma unroll
    for (int n = 0; n < 4; ++n)
      bfr[n] = *reinterpret_cast<const bf16x8*>(lds + 8192 + (wc * 64 + n * 16 + lrow) * 64 + lk * 16);
#pragma unroll
    for (int m = 0; m < 4; ++m)
#pragma unroll
      for (int n = 0; n < 4; ++n)
        acc[m][n] = __builtin_amdgcn_mfma_f32_16x16x32_bf16(af[m], bfr[n], acc[m][n], 0, 0, 0);
  }

  // ---- RoPE in place (pairs (0,2) and (1,3) share one lane) ----
  const float LG = 0.41524101186f;               // log2(10000)/32
  float invf0 = exp2f(-(float)lrow * LG);
  float invf1 = exp2f(-(float)(lrow + 16) * LG);
#pragma unroll
  for (int m = 0; m < 4; ++m)
#pragma unroll
    for (int r = 0; r < 4; ++r) {
      int rl = wr * 64 + m * 16 + lk * 4 + r;
      int pos = isq ? (HISTC + ((m0 + rl) & 1023)) : ((m0 + rl) & 4095);
      float fp = (float)pos;
      float s0, c0, s1, c1;
      sincosf(fp * invf0, &s0, &c0);
      sincosf(fp * invf1, &s1, &c1);
      float a0 = acc[m][0][r], a2 = acc[m][2][r];
      acc[m][0][r] = a0 * c0 - a2 * s0;
      acc[m][2][r] = a2 * c0 + a0 * s0;
      float a1 = acc[m][1][r], a3 = acc[m][3][r];
      acc[m][1][r] = a1 * c1 - a3 * s1;
      acc[m][3][r] = a3 * c1 + a1 * s1;
    }

  const int h = (n0 + wc * 64) >> 6;
  if (!isq) {
    // ---- per-head LayerNorm over the 64 cols (16-lane reduction) ----
    float g4[4], b4[4];
#pragma unroll
    for (int n = 0; n < 4; ++n) { g4[n] = gamma[n * 16 + lrow]; b4[n] = beta[n * 16 + lrow]; }
#pragma unroll
    for (int m = 0; m < 4; ++m)
#pragma unroll
      for (int r = 0; r < 4; ++r) {
        float s1 = acc[m][0][r] + acc[m][1][r] + acc[m][2][r] + acc[m][3][r];
        float s2 = acc[m][0][r] * acc[m][0][r] + acc[m][1][r] * acc[m][1][r] +
                   acc[m][2][r] * acc[m][2][r] + acc[m][3][r] * acc[m][3][r];
#pragma unroll
        for (int mk = 1; mk < 16; mk <<= 1) {
          s1 += __shfl_xor(s1, mk);
          s2 += __shfl_xor(s2, mk);
        }
        float mu = s1 * 0.015625f;
        float var = s2 * 0.015625f - mu * mu;
        float inv = rsqrtf(var + 1e-5f);
#pragma unroll
        for (int n = 0; n < 4; ++n)
          acc[m][n][r] = (acc[m][n][r] - mu) * inv * g4[n] + b4[n];
      }
    const size_t hb = (size_t)((m0 >> 12) * HEADS + h);
    // kvn [b,h,pos,d]
#pragma unroll
    for (int m = 0; m < 4; ++m)
#pragma unroll
      for (int r = 0; r < 4; ++r) {
        int pos = (m0 + wr * 64 + m * 16 + lk * 4 + r) & 4095;
#pragma unroll
        for (int n = 0; n < 4; ++n)
          kvn[(hb * SEQ + pos) * DHH + n * 16 + lrow] = (__bf16)acc[m][n][r];
      }
    // kvnT [b,h,d,sigma(pos)] : r-quads stay contiguous under sigma (bits 2,3 swap)
#pragma unroll
    for (int m = 0; m < 4; ++m) {
      int pos0 = (m0 + wr * 64 + m * 16 + lk * 4) & 4095;
      int sp = (pos0 & ~12) | ((pos0 & 4) << 1) | ((pos0 & 8) >> 1);
#pragma unroll
      for (int n = 0; n < 4; ++n) {
        union { __bf16 hh[4]; uint64_t u; } pk;
#pragma unroll
        for (int r = 0; r < 4; ++r) pk.hh[r] = (__bf16)acc[m][n][r];
        *reinterpret_cast<uint64_t*>(kvnT + (hb * DHH + n * 16 + lrow) * SEQ + sp) = pk.u;
      }
    }
  } else {
    // ---- q: scale by DH^-0.5 * log2(e), write qb [b,h,i,d] ----
    const size_t hb = (size_t)((m0 >> 10) * HEADS + h);
#pragma unroll
    for (int m = 0; m < 4; ++m)
#pragma unroll
      for (int r = 0; r < 4; ++r) {
        int qi = (m0 + wr * 64 + m * 16 + lk * 4 + r) & 1023;
#pragma unroll
        for (int n = 0; n < 4; ++n)
          qb[(hb * LATENT + qi) * DHH + n * 16 + lrow] =
              (__bf16)(acc[m][n][r] * 0.18033688011112042f);
      }
  }
}

// ---------------- helpers for flash ----------------
__device__ __forceinline__ float fexp2(float x) {
#if __has_builtin(__builtin_amdgcn_exp2f)
  return __builtin_amdgcn_exp2f(x);
#else
  return exp2f(x);
#endif
}

__device__ __forceinline__ unsigned pk2(float a, float b) {
  union { __bf16 h[2]; unsigned u; } x;
  x.h[0] = (__bf16)a; x.h[1] = (__bf16)b;
  return x.u;
}

// ---------------- flash attention v7 ----------------
// flash5 (proven 92us) widened to 64-key iterations: two 32-key subtiles a/b
// per trip. Same math/layouts per subtile; K(a) prefetched a full iteration
// ahead, K(b)/V(a,b) ~0.7 iteration ahead. Doubles independent work between
// dependent ops; halves loop overhead.
__launch_bounds__(256)
__global__ void k_flash7(const __bf16* __restrict__ qb, const __bf16* __restrict__ kvn,
                         const __bf16* __restrict__ kvnT, __bf16* __restrict__ aout) {
  const int bid = blockIdx.x;
  const int bh = (bid & 7) + 8 * (bid >> 8);
  const int itile = (bid >> 3) & 31;
  const int h = bh & 15, b = bh >> 4;
  const int t = threadIdx.x, l = t & 63, w = t >> 6;
  const int q = l & 31, hi = l >> 5;
  const int iw = itile * 32;
  const int i = iw + q;
  const __bf16* qbase = qb + ((size_t)(b * HEADS + h) * LATENT + iw) * DHH;
  const __bf16* kbase = kvn + (size_t)(b * HEADS + h) * SEQ * DHH;
  const __bf16* vbase = kvnT + (size_t)(b * HEADS + h) * DHH * SEQ;

  __shared__ __align__(16) char smem[4][8192];   // per-wave: Va[64][32] | Vb[64][32]; merge Ow overlays
  __shared__ float Mlds[4][32];
  __shared__ float Llds[4][32];
  __bf16 (*Va)[32] = reinterpret_cast<__bf16(*)[32]>(smem[w]);
  __bf16 (*Vb)[32] = reinterpret_cast<__bf16(*)[32]>(smem[w] + 4096);

  bf16x8 qf[4];
#pragma unroll
  for (int c = 0; c < 4; ++c)
    qf[c] = *reinterpret_cast<const bf16x8*>(qbase + (size_t)q * DHH + c * 16 + hi * 8);

  const f32x16 Z = {};
  f32x16 O0 = {}, O1 = {};
  float m_run = -INFINITY, lacc = 0.f;

  const int nt64 = (itile + 98) >> 1;            // 64-key tiles (last may overhang; masked)
  const int g0 = (nt64 * w) >> 2, g1 = (nt64 * (w + 1)) >> 2;

  const int srow = l >> 2, scol = l & 3;
  const int wchunk = (scol ^ (srow & 3)) * 8;    // LDS write swizzle (as flash5)
  const int sx = q & 3;

  // V staging global addresses: lane covers row ii*16+srow, 16B chunk scol
  const __bf16* vstg = vbase + (size_t)srow * SEQ + scol * 8;
  const __bf16* kptr = kbase + (size_t)q * DHH + hi * 8;

  bf16x8 vra[4], vrb[4], kra[4], krb[4];
#pragma unroll
  for (int ii = 0; ii < 4; ++ii) {
    vra[ii] = *reinterpret_cast<const bf16x8*>(vstg + (size_t)(ii * 16) * SEQ + g0 * 64);
    vrb[ii] = *reinterpret_cast<const bf16x8*>(vstg + (size_t)(ii * 16) * SEQ + g0 * 64 + 32);
  }
#pragma unroll
  for (int c = 0; c < 4; ++c) {
    kra[c] = *reinterpret_cast<const bf16x8*>(kptr + (size_t)(g0 * 64) * DHH + c * 16);
    krb[c] = *reinterpret_cast<const bf16x8*>(kptr + (size_t)(g0 * 64 + 32) * DHH + c * 16);
  }

  for (int g = g0; g < g1; ++g) {
    const int ja = g * 64, jb = ja + 32;
    const int gn = (g + 1 < g1) ? g + 1 : g;
    // commit V(g) subtiles into LDS (wave-private, in-order DS)
#pragma unroll
    for (int ii = 0; ii < 4; ++ii) {
      *reinterpret_cast<bf16x8*>(&Va[ii * 16 + srow][wchunk]) = vra[ii];
      *reinterpret_cast<bf16x8*>(&Vb[ii * 16 + srow][wchunk]) = vrb[ii];
    }
    // ---------------- subtile a ----------------
    f32x16 S = __builtin_amdgcn_mfma_f32_32x32x16_bf16(kra[0], qf[0], Z, 0, 0, 0);
    S = __builtin_amdgcn_mfma_f32_32x32x16_bf16(kra[1], qf[1], S, 0, 0, 0);
    S = __builtin_amdgcn_mfma_f32_32x32x16_bf16(kra[2], qf[2], S, 0, 0, 0);
    S = __builtin_amdgcn_mfma_f32_32x32x16_bf16(kra[3], qf[3], S, 0, 0, 0);
    // prefetch K(a) of next iter (full-iteration distance)
#pragma unroll
    for (int c = 0; c < 4; ++c)
      kra[c] = *reinterpret_cast<const bf16x8*>(kptr + (size_t)(gn * 64) * DHH + c * 16);
    if (ja + 31 > iw + HISTC) {
#pragma unroll
      for (int r = 0; r < 16; ++r) {
        int j = ja + (r & 3) + 8 * (r >> 2) + 4 * hi;
        if (j > i + HISTC) S[r] = -1e30f;
      }
    }
    {
      float u1 = fmaxf(fmaxf(S[0], S[1]), S[2]);
      float u2 = fmaxf(fmaxf(S[3], S[4]), S[5]);
      float u3 = fmaxf(fmaxf(S[6], S[7]), S[8]);
      float u4 = fmaxf(fmaxf(S[9], S[10]), S[11]);
      float u5 = fmaxf(fmaxf(S[12], S[13]), S[14]);
      float pm = fmaxf(fmaxf(fmaxf(u1, u2), u3), fmaxf(fmaxf(u4, u5), S[15]));
      if (__any(pm > m_run + 8.0f)) {
        pm = fmaxf(pm, __shfl_xor(pm, 32));
        float mn = fmaxf(m_run, pm);
        float sc = fexp2(m_run - mn);
        m_run = mn;
        lacc *= sc;
#pragma unroll
        for (int r = 0; r < 16; ++r) { O0[r] *= sc; O1[r] *= sc; }
      }
      float p[16];
#pragma unroll
      for (int r = 0; r < 16; ++r) p[r] = fexp2(S[r] - m_run);
      float s8[8];
#pragma unroll
      for (int r = 0; r < 8; ++r) s8[r] = p[r] + p[r + 8];
      lacc += ((s8[0] + s8[4]) + (s8[1] + s8[5])) + ((s8[2] + s8[6]) + (s8[3] + s8[7]));
      union { unsigned u[4]; bf16x8 v; } pf0, pf1;
      pf0.u[0] = pk2(p[0], p[1]);   pf0.u[1] = pk2(p[2], p[3]);
      pf0.u[2] = pk2(p[4], p[5]);   pf0.u[3] = pk2(p[6], p[7]);
      pf1.u[0] = pk2(p[8], p[9]);   pf1.u[1] = pk2(p[10], p[11]);
      pf1.u[2] = pk2(p[12], p[13]); pf1.u[3] = pk2(p[14], p[15]);
      bf16x8 va00 = *reinterpret_cast<const bf16x8*>(&Va[q][(hi ^ sx) * 8]);
      bf16x8 va01 = *reinterpret_cast<const bf16x8*>(&Va[q][((2 + hi) ^ sx) * 8]);
      bf16x8 va10 = *reinterpret_cast<const bf16x8*>(&Va[32 + q][(hi ^ sx) * 8]);
      bf16x8 va11 = *reinterpret_cast<const bf16x8*>(&Va[32 + q][((2 + hi) ^ sx) * 8]);
      O0 = __builtin_amdgcn_mfma_f32_32x32x16_bf16(va00, pf0.v, O0, 0, 0, 0);
      O0 = __builtin_amdgcn_mfma_f32_32x32x16_bf16(va01, pf1.v, O0, 0, 0, 0);
      O1 = __builtin_amdgcn_mfma_f32_32x32x16_bf16(va10, pf0.v, O1, 0, 0, 0);
      O1 = __builtin_amdgcn_mfma_f32_32x32x16_bf16(va11, pf1.v, O1, 0, 0, 0);
    }
    // ---------------- subtile b ----------------
    f32x16 T = __builtin_amdgcn_mfma_f32_32x32x16_bf16(krb[0], qf[0], Z, 0, 0, 0);
    T = __builtin_amdgcn_mfma_f32_32x32x16_bf16(krb[1], qf[1], T, 0, 0, 0);
    T = __builtin_amdgcn_mfma_f32_32x32x16_bf16(krb[2], qf[2], T, 0, 0, 0);
    T = __builtin_amdgcn_mfma_f32_32x32x16_bf16(krb[3], qf[3], T, 0, 0, 0);
    // prefetch K(b) and V(a,b) of next iter
#pragma unroll
    for (int c = 0; c < 4; ++c)
      krb[c] = *reinterpret_cast<const bf16x8*>(kptr + (size_t)(gn * 64 + 32) * DHH + c * 16);
#pragma unroll
    for (int ii = 0; ii < 4; ++ii) {
      vra[ii] = *reinterpret_cast<const bf16x8*>(vstg + (size_t)(ii * 16) * SEQ + gn * 64);
      vrb[ii] = *reinterpret_cast<const bf16x8*>(vstg + (size_t)(ii * 16) * SEQ + gn * 64 + 32);
    }
    if (jb + 31 > iw + HISTC) {
#pragma unroll
      for (int r = 0; r < 16; ++r) {
        int j = jb + (r & 3) + 8 * (r >> 2) + 4 * hi;
        if (j > i + HISTC) T[r] = -1e30f;
      }
    }
    {
      float u1 = fmaxf(fmaxf(T[0], T[1]), T[2]);
      float u2 = fmaxf(fmaxf(T[3], T[4]), T[5]);
      float u3 = fmaxf(fmaxf(T[6], T[7]), T[8]);
      float u4 = fmaxf(fmaxf(T[9], T[10]), T[11]);
      float u5 = fmaxf(fmaxf(T[12], T[13]), T[14]);
      float pm = fmaxf(fmaxf(fmaxf(u1, u2), u3), fmaxf(fmaxf(u4, u5), T[15]));
      if (__any(pm > m_run + 8.0f)) {
        pm = fmaxf(pm, __shfl_xor(pm, 32));
        float mn = fmaxf(m_run, pm);
        float sc = fexp2(m_run - mn);
        m_run = mn;
        lacc *= sc;
#pragma unroll
        for (int r = 0; r < 16; ++r) { O0[r] *= sc; O1[r] *= sc; }
      }
      float p[16];
#pragma unroll
      for (int r = 0; r < 16; ++r) p[r] = fexp2(T[r] - m_run);
      float s8[8];
#pragma unroll
      for (int r = 0; r < 8; ++r) s8[r] = p[r] + p[r + 8];
      lacc += ((s8[0] + s8[4]) + (s8[1] + s8[5])) + ((s8[2] + s8[6]) + (s8[3] + s8[7]));
      union { unsigned u[4]; bf16x8 v; } pf0, pf1;
      pf0.u[0] = pk2(p[0], p[1]);   pf0.u[1] = pk2(p[2], p[3]);
      pf0.u[2] = pk2(p[4], p[5]);   pf0.u[3] = pk2(p[6], p[7]);
      pf1.u[0] = pk2(p[8], p[9]);   pf1.u[1] = pk2(p[10], p[11]);
      pf1.u[2] = pk2(p[12], p[13]); pf1.u[3] = pk2(p[14], p[15]);
      bf16x8 vb00 = *reinterpret_cast<const bf16x8*>(&Vb[q][(hi ^ sx) * 8]);
      bf16x8 vb01 = *reinterpret_cast<const bf16x8*>(&Vb[q][((2 + hi) ^ sx) * 8]);
      bf16x8 vb10 = *reinterpret_cast<const bf16x8*>(&Vb[32 + q][(hi ^ sx) * 8]);
      bf16x8 vb11 = *reinterpret_cast<const bf16x8*>(&Vb[32 + q][((2 + hi) ^ sx) * 8]);
      O0 = __builtin_amdgcn_mfma_f32_32x32x16_bf16(vb00, pf0.v, O0, 0, 0, 0);
      O0 = __builtin_amdgcn_mfma_f32_32x32x16_bf16(vb01, pf1.v, O0, 0, 0, 0);
      O1 = __builtin_amdgcn_mfma_f32_32x32x16_bf16(vb10, pf0.v, O1, 0, 0, 0);
      O1 = __builtin_amdgcn_mfma_f32_32x32x16_bf16(vb11, pf1.v, O1, 0, 0, 0);
    }
  }
  float l_run = lacc + __shfl_xor(lacc, 32);

  // -------- merge the 4 waves' partial (O, m, l), chunked over d --------
  float (*Ow)[33] = reinterpret_cast<float(*)[33]>(smem[w]);   // overlays Va (dead)
  if (hi == 0) { Mlds[w][q] = m_run; Llds[w][q] = l_run; }
#pragma unroll
  for (int r = 0; r < 16; ++r)
    Ow[q][(r & 3) + 8 * (r >> 2) + 4 * hi] = O0[r];
  __syncthreads();
  const int mi = t >> 3, dl = (t & 7) * 4;
  float m0v = Mlds[0][mi], m1v = Mlds[1][mi], m2v = Mlds[2][mi], m3v = Mlds[3][mi];
  float mm = fmaxf(fmaxf(m0v, m1v), fmaxf(m2v, m3v));
  float sc0 = fexp2(m0v - mm), sc1 = fexp2(m1v - mm);
  float sc2 = fexp2(m2v - mm), sc3 = fexp2(m3v - mm);
  float ll = Llds[0][mi] * sc0 + Llds[1][mi] * sc1 + Llds[2][mi] * sc2 + Llds[3][mi] * sc3;
  float inv = 1.f / ll;
  __bf16* orow = aout + ((size_t)(b * LATENT) + iw + mi) * DIMC + h * DHH;
  {
    float(*O0p)[33] = reinterpret_cast<float(*)[33]>(smem[0]);
    float(*O1p)[33] = reinterpret_cast<float(*)[33]>(smem[1]);
    float(*O2p)[33] = reinterpret_cast<float(*)[33]>(smem[2]);
    float(*O3p)[33] = reinterpret_cast<float(*)[33]>(smem[3]);
    union { __bf16 hh[4]; uint2 u2; } pkv;
#pragma unroll
    for (int e = 0; e < 4; ++e) {
      float o = O0p[mi][dl + e] * sc0 + O1p[mi][dl + e] * sc1 +
                O2p[mi][dl + e] * sc2 + O3p[mi][dl + e] * sc3;
      pkv.hh[e] = (__bf16)(o * inv);
    }
    *reinterpret_cast<uint2*>(orow + dl) = pkv.u2;
  }
  __syncthreads();
#pragma unroll
  for (int r = 0; r < 16; ++r)
    Ow[q][(r & 3) + 8 * (r >> 2) + 4 * hi] = O1[r];
  __syncthreads();
  {
    float(*O0p)[33] = reinterpret_cast<float(*)[33]>(smem[0]);
    float(*O1p)[33] = reinterpret_cast<float(*)[33]>(smem[1]);
    float(*O2p)[33] = reinterpret_cast<float(*)[33]>(smem[2]);
    float(*O3p)[33] = reinterpret_cast<float(*)[33]>(smem[3]);
    union { __bf16 hh[4]; uint2 u2; } pkv;
#pragma unroll
    for (int e = 0; e < 4; ++e) {
      float o = O0p[mi][dl + e] * sc0 + O1p[mi][dl + e] * sc1 +
                O2p[mi][dl + e] * sc2 + O3p[mi][dl + e] * sc3;
      pkv.hh[e] = (__bf16)(o * inv);
    }
    *reinterpret_cast<uint2*>(orow + 32 + dl) = pkv.u2;
  }
}

// ---------------- host launcher ----------------
extern "C" void kernel_launch(void* const* d_in, const int* in_sizes, int n_in,
                              void* d_out, int out_size, void* d_ws, size_t ws_size,
                              hipStream_t stream) {
  const float* x = (const float*)d_in[0];
  const float* Wq = (const float*)d_in[1];
  const float* Wkv = (const float*)d_in[2];
  const float* Wo = (const float*)d_in[3];
  const float* bo = (const float*)d_in[4];
  const float* gamma = (const float*)d_in[5];
  const float* beta = (const float*)d_in[6];

  char* ws = (char*)d_ws;
  size_t o = 0;
  __bf16* x16 = (__bf16*)(ws + o);  o += (size_t)BATCH * SEQ * DIMC * 2;
  __bf16* wq16 = (__bf16*)(ws + o); o += (size_t)DIMC * DIMC * 2;
  __bf16* wkv16 = (__bf16*)(ws + o); o += (size_t)DIMC * DIMC * 2;
  __bf16* wo16 = (__bf16*)(ws + o); o += (size_t)DIMC * DIMC * 2;
  __bf16* kvn = (__bf16*)(ws + o);  o += (size_t)BATCH * HEADS * SEQ * DHH * 2;
  __bf16* kvnT = (__bf16*)(ws + o); o += (size_t)BATCH * HEADS * SEQ * DHH * 2;
  __bf16* qb = (__bf16*)(ws + o);   o += (size_t)BATCH * HEADS * LATENT * DHH * 2;
  __bf16* aout = (__bf16*)(ws + o); o += (size_t)BATCH * LATENT * DIMC * 2;

  k_convert<<<2048, 256, 0, stream>>>(x, x16, BATCH * SEQ * DIMC);
  k_convert3<<<1536, 256, 0, stream>>>(Wq, Wkv, Wo, wq16, wkv16, wo16);
  k_gemmqkv<<<dim3(8, 80), 256, 0, stream>>>(x16, wkv16, wq16, kvn, kvnT, qb, gamma, beta);
  k_flash7<<<1024, 256, 0, stream>>>(qb, kvn, kvnT, aout);
  k_gemm<0, 1><<<dim3(8, 16), 256, 0, stream>>>(aout, wo16, (float*)d_out, bo, 2048, 1024, 1024);
}

// Round 9
// 171.095 us; speedup vs baseline: 1.2350x; 1.0178x over previous
//
#include <hip/hip_runtime.h>
#include <hip/hip_bf16.h>
#include <cstdint>

#define DIMC 1024
#define HEADS 16
#define DHH 64
#define SEQ 4096
#define LATENT 1024
#define HISTC 3072
#define BATCH 2

typedef __attribute__((ext_vector_type(8))) __bf16 bf16x8;
typedef __attribute__((ext_vector_type(4))) float f32x4;
typedef __attribute__((ext_vector_type(16))) float f32x16;

// ---------------- fp32 -> bf16 convert (vectorized) ----------------
__global__ void k_convert(const float* __restrict__ in, __bf16* __restrict__ out, int n) {
  int stride = gridDim.x * blockDim.x;
  int nc = n >> 2;
  for (int i = blockIdx.x * blockDim.x + threadIdx.x; i < nc; i += stride) {
    float4 v = reinterpret_cast<const float4*>(in)[i];
    union { __bf16 h[4]; uint64_t u; } p;
    p.h[0] = (__bf16)v.x; p.h[1] = (__bf16)v.y;
    p.h[2] = (__bf16)v.z; p.h[3] = (__bf16)v.w;
    reinterpret_cast<uint64_t*>(out)[i] = p.u;
  }
}

// three weight matrices (1024x1024 each) in one launch
__global__ void k_convert3(const float* __restrict__ a, const float* __restrict__ b,
                           const float* __restrict__ c, __bf16* __restrict__ oa,
                           __bf16* __restrict__ ob, __bf16* __restrict__ oc) {
  int id = blockIdx.x;
  const float* src; __bf16* dst;
  if (id < 512) { src = a; dst = oa; }
  else if (id < 1024) { src = b; dst = ob; id -= 512; }
  else { src = c; dst = oc; id -= 1024; }
#pragma unroll
  for (int k = 0; k < 2; ++k) {
    int idx = id * 512 + k * 256 + threadIdx.x;
    float4 v = reinterpret_cast<const float4*>(src)[idx];
    union { __bf16 h[4]; uint64_t u; } p;
    p.h[0] = (__bf16)v.x; p.h[1] = (__bf16)v.y;
    p.h[2] = (__bf16)v.z; p.h[3] = (__bf16)v.w;
    reinterpret_cast<uint64_t*>(dst)[idx] = p.u;
  }
}

// ---------------- RoPE cos/sin table: cs[pos*32+f] = {cos,sin}(pos * 10000^(-f/32)) ----
__global__ void k_cstab(float2* __restrict__ cs) {
  int idx = blockIdx.x * 256 + threadIdx.x;      // 4096*32 entries
  int pos = idx >> 5, f = idx & 31;
  float invf = exp2f(-(float)f * 0.41524101186f);  // log2(10000)/32
  float s, c;
  sincosf((float)pos * invf, &s, &c);
  cs[idx] = make_float2(c, s);
}

// ---------------- async global->LDS 16B ----------------
__device__ __forceinline__ void gload16(void* lds, const void* g) {
  __builtin_amdgcn_global_load_lds(
      (const __attribute__((address_space(1))) unsigned int*)g,
      (__attribute__((address_space(3))) unsigned int*)lds, 16, 0, 0);
}

// ---------------- plain GEMM (used for o-proj): C = A @ Bw^T + bias ----
template<int QREMAP, int BIAS>
__launch_bounds__(256)
__global__ void k_gemm(const __bf16* __restrict__ A, const __bf16* __restrict__ Bw,
                       float* __restrict__ C, const float* __restrict__ bias,
                       int M, int N, int K) {
  __shared__ __align__(16) char lds[16384];
  const int t = threadIdx.x;
  const int l = t & 63, w = t >> 6;
  const int wr = w >> 1, wc = w & 1;
  const int m0 = blockIdx.y * 128, n0 = blockIdx.x * 128;
  const int lrow = l & 15, lk = l >> 4;
  f32x4 acc[4][4] = {};

  for (int k0 = 0; k0 < K; k0 += 32) {
    if (k0) __syncthreads();
#pragma unroll
    for (int i = 0; i < 2; ++i) {
      int c = i * 256 + t;
      int row = c >> 2, kc = c & 3;
      int mi = m0 + row;
      if (QREMAP) mi += HISTC + (mi >> 10) * HISTC;
      gload16(lds + c * 16, A + (size_t)mi * K + k0 + kc * 8);
      gload16(lds + 8192 + c * 16, Bw + (size_t)(n0 + row) * K + k0 + kc * 8);
    }
    __syncthreads();
    bf16x8 af[4], bfr[4];
#pragma unroll
    for (int m = 0; m < 4; ++m)
      af[m] = *reinterpret_cast<const bf16x8*>(lds + (wr * 64 + m * 16 + lrow) * 64 + lk * 16);
#pragma unroll
    for (int n = 0; n < 4; ++n)
      bfr[n] = *reinterpret_cast<const bf16x8*>(lds + 8192 + (wc * 64 + n * 16 + lrow) * 64 + lk * 16);
#pragma unroll
    for (int m = 0; m < 4; ++m)
#pragma unroll
      for (int n = 0; n < 4; ++n)
        acc[m][n] = __builtin_amdgcn_mfma_f32_16x16x32_bf16(af[m], bfr[n], acc[m][n], 0, 0, 0);
  }

#pragma unroll
  for (int m = 0; m < 4; ++m)
#pragma unroll
    for (int n = 0; n < 4; ++n)
#pragma unroll
      for (int r = 0; r < 4; ++r) {
        int row = m0 + wr * 64 + m * 16 + (l >> 4) * 4 + r;
        int col = n0 + wc * 64 + n * 16 + (l & 15);
        float v = acc[m][n][r];
        if (BIAS) v += bias[col];
        C[(size_t)row * N + col] = v;
      }
}

// ---------------- fused QKV GEMM: kv-proj(+RoPE+LN) and q-proj(+RoPE+scale) ----
// RoPE cos/sin from precomputed table (was: 32 libm sincosf per thread).
__launch_bounds__(256)
__global__ void k_gemmqkv(const __bf16* __restrict__ x16,
                          const __bf16* __restrict__ wkv16,
                          const __bf16* __restrict__ wq16,
                          __bf16* __restrict__ kvn, __bf16* __restrict__ kvnT,
                          __bf16* __restrict__ qb,
                          const float* __restrict__ gamma,
                          const float* __restrict__ beta,
                          const float2* __restrict__ cstab) {
  __shared__ __align__(16) char lds[16384];
  const int t = threadIdx.x, l = t & 63, w = t >> 6;
  const int wr = w >> 1, wc = w & 1;
  const int by = blockIdx.y;
  const bool isq = by >= 64;
  const int m0 = (isq ? (by - 64) : by) * 128;
  const int n0 = blockIdx.x * 128;
  const __bf16* Bw = isq ? wq16 : wkv16;
  const int lrow = l & 15, lk = l >> 4;
  f32x4 acc[4][4] = {};

  for (int k0 = 0; k0 < 1024; k0 += 32) {
    if (k0) __syncthreads();
#pragma unroll
    for (int i = 0; i < 2; ++i) {
      int c = i * 256 + t;
      int row = c >> 2, kc = c & 3;
      int mi = m0 + row;
      if (isq) mi += HISTC + (mi >> 10) * HISTC;
      gload16(lds + c * 16, x16 + (size_t)mi * 1024 + k0 + kc * 8);
      gload16(lds + 8192 + c * 16, Bw + (size_t)(n0 + row) * 1024 + k0 + kc * 8);
    }
    __syncthreads();
    bf16x8 af[4], bfr[4];
#pragma unroll
    for (int m = 0; m < 4; ++m)
      af[m] = *reinterpret_cast<const bf16x8*>(lds + (wr * 64 + m * 16 + lrow) * 64 + lk * 16);
#pragma unroll
    for (int n = 0; n < 4; ++n)
      bfr[n] = *reinterpret_cast<const bf16x8*>(lds + 8192 + (wc * 64 + n * 16 + lrow) * 64 + lk * 16);
#pragma unroll
    for (int m = 0; m < 4; ++m)
#pragma unroll
      for (int n = 0; n < 4; ++n)
        acc[m][n] = __builtin_amdgcn_mfma_f32_16x16x32_bf16(af[m], bfr[n], acc[m][n], 0, 0, 0);
  }

  // ---- RoPE in place via table (pairs (0,2) and (1,3) share one lane) ----
#pragma unroll
  for (int m = 0; m < 4; ++m)
#pragma unroll
    for (int r = 0; r < 4; ++r) {
      int rl = wr * 64 + m * 16 + lk * 4 + r;
      int pos = isq ? (HISTC + ((m0 + rl) & 1023)) : ((m0 + rl) & 4095);
      float2 cs0 = cstab[pos * 32 + lrow];
      float2 cs1 = cstab[pos * 32 + 16 + lrow];
      float a0 = acc[m][0][r], a2 = acc[m][2][r];
      acc[m][0][r] = a0 * cs0.x - a2 * cs0.y;
      acc[m][2][r] = a2 * cs0.x + a0 * cs0.y;
      float a1 = acc[m][1][r], a3 = acc[m][3][r];
      acc[m][1][r] = a1 * cs1.x - a3 * cs1.y;
      acc[m][3][r] = a3 * cs1.x + a1 * cs1.y;
    }

  const int h = (n0 + wc * 64) >> 6;
  if (!isq) {
    // ---- per-head LayerNorm over the 64 cols (16-lane reduction) ----
    float g4[4], b4[4];
#pragma unroll
    for (int n = 0; n < 4; ++n) { g4[n] = gamma[n * 16 + lrow]; b4[n] = beta[n * 16 + lrow]; }
#pragma unroll
    for (int m = 0; m < 4; ++m)
#pragma unroll
      for (int r = 0; r < 4; ++r) {
        float s1 = acc[m][0][r] + acc[m][1][r] + acc[m][2][r] + acc[m][3][r];
        float s2 = acc[m][0][r] * acc[m][0][r] + acc[m][1][r] * acc[m][1][r] +
                   acc[m][2][r] * acc[m][2][r] + acc[m][3][r] * acc[m][3][r];
#pragma unroll
        for (int mk = 1; mk < 16; mk <<= 1) {
          s1 += __shfl_xor(s1, mk);
          s2 += __shfl_xor(s2, mk);
        }
        float mu = s1 * 0.015625f;
        float var = s2 * 0.015625f - mu * mu;
        float inv = rsqrtf(var + 1e-5f);
#pragma unroll
        for (int n = 0; n < 4; ++n)
          acc[m][n][r] = (acc[m][n][r] - mu) * inv * g4[n] + b4[n];
      }
    const size_t hb = (size_t)((m0 >> 12) * HEADS + h);
    // kvn [b,h,pos,d]
#pragma unroll
    for (int m = 0; m < 4; ++m)
#pragma unroll
      for (int r = 0; r < 4; ++r) {
        int pos = (m0 + wr * 64 + m * 16 + lk * 4 + r) & 4095;
#pragma unroll
        for (int n = 0; n < 4; ++n)
          kvn[(hb * SEQ + pos) * DHH + n * 16 + lrow] = (__bf16)acc[m][n][r];
      }
    // kvnT [b,h,d,sigma(pos)] : r-quads stay contiguous under sigma (bits 2,3 swap)
#pragma unroll
    for (int m = 0; m < 4; ++m) {
      int pos0 = (m0 + wr * 64 + m * 16 + lk * 4) & 4095;
      int sp = (pos0 & ~12) | ((pos0 & 4) << 1) | ((pos0 & 8) >> 1);
#pragma unroll
      for (int n = 0; n < 4; ++n) {
        union { __bf16 hh[4]; uint64_t u; } pk;
#pragma unroll
        for (int r = 0; r < 4; ++r) pk.hh[r] = (__bf16)acc[m][n][r];
        *reinterpret_cast<uint64_t*>(kvnT + (hb * DHH + n * 16 + lrow) * SEQ + sp) = pk.u;
      }
    }
  } else {
    // ---- q: scale by DH^-0.5 * log2(e), write qb [b,h,i,d] ----
    const size_t hb = (size_t)((m0 >> 10) * HEADS + h);
#pragma unroll
    for (int m = 0; m < 4; ++m)
#pragma unroll
      for (int r = 0; r < 4; ++r) {
        int qi = (m0 + wr * 64 + m * 16 + lk * 4 + r) & 1023;
#pragma unroll
        for (int n = 0; n < 4; ++n)
          qb[(hb * LATENT + qi) * DHH + n * 16 + lrow] =
              (__bf16)(acc[m][n][r] * 0.18033688011112042f);
      }
  }
}

// ---------------- helpers for flash ----------------
__device__ __forceinline__ float fexp2(float x) {
#if __has_builtin(__builtin_amdgcn_exp2f)
  return __builtin_amdgcn_exp2f(x);
#else
  return exp2f(x);
#endif
}

__device__ __forceinline__ unsigned pk2(float a, float b) {
  union { __bf16 h[2]; unsigned u; } x;
  x.h[0] = (__bf16)a; x.h[1] = (__bf16)b;
  return x.u;
}

// ---------------- flash attention v7b ----------------
// flash7 + itile anti-straggler flip: round-robin CU assignment gives each CU
// 4 blocks of the SAME itile (work ~ itile+97) -> 30% tail. Flipping itile for
// odd g-groups makes every CU's 4-block work sum constant (450 tile-units).
__launch_bounds__(256)
__global__ void k_flash7(const __bf16* __restrict__ qb, const __bf16* __restrict__ kvn,
                         const __bf16* __restrict__ kvnT, __bf16* __restrict__ aout) {
  const int bid = blockIdx.x;
  const int g = bid >> 8;
  const int bh = (bid & 7) + 8 * g;
  int itile = (bid >> 3) & 31;
  if (g & 1) itile = 31 - itile;                 // balance work across CUs
  const int h = bh & 15, b = bh >> 4;
  const int t = threadIdx.x, l = t & 63, w = t >> 6;
  const int q = l & 31, hi = l >> 5;
  const int iw = itile * 32;
  const int i = iw + q;
  const __bf16* qbase = qb + ((size_t)(b * HEADS + h) * LATENT + iw) * DHH;
  const __bf16* kbase = kvn + (size_t)(b * HEADS + h) * SEQ * DHH;
  const __bf16* vbase = kvnT + (size_t)(b * HEADS + h) * DHH * SEQ;

  __shared__ __align__(16) char smem[4][8192];   // per-wave: Va[64][32] | Vb[64][32]; merge Ow overlays
  __shared__ float Mlds[4][32];
  __shared__ float Llds[4][32];
  __bf16 (*Va)[32] = reinterpret_cast<__bf16(*)[32]>(smem[w]);
  __bf16 (*Vb)[32] = reinterpret_cast<__bf16(*)[32]>(smem[w] + 4096);

  bf16x8 qf[4];
#pragma unroll
  for (int c = 0; c < 4; ++c)
    qf[c] = *reinterpret_cast<const bf16x8*>(qbase + (size_t)q * DHH + c * 16 + hi * 8);

  const f32x16 Z = {};
  f32x16 O0 = {}, O1 = {};
  float m_run = -INFINITY, lacc = 0.f;

  const int nt64 = (itile + 98) >> 1;            // 64-key tiles (last may overhang; masked)
  const int g0 = (nt64 * w) >> 2, g1 = (nt64 * (w + 1)) >> 2;

  const int srow = l >> 2, scol = l & 3;
  const int wchunk = (scol ^ (srow & 3)) * 8;    // LDS write swizzle
  const int sx = q & 3;

  const __bf16* vstg = vbase + (size_t)srow * SEQ + scol * 8;
  const __bf16* kptr = kbase + (size_t)q * DHH + hi * 8;

  bf16x8 vra[4], vrb[4], kra[4], krb[4];
#pragma unroll
  for (int ii = 0; ii < 4; ++ii) {
    vra[ii] = *reinterpret_cast<const bf16x8*>(vstg + (size_t)(ii * 16) * SEQ + g0 * 64);
    vrb[ii] = *reinterpret_cast<const bf16x8*>(vstg + (size_t)(ii * 16) * SEQ + g0 * 64 + 32);
  }
#pragma unroll
  for (int c = 0; c < 4; ++c) {
    kra[c] = *reinterpret_cast<const bf16x8*>(kptr + (size_t)(g0 * 64) * DHH + c * 16);
    krb[c] = *reinterpret_cast<const bf16x8*>(kptr + (size_t)(g0 * 64 + 32) * DHH + c * 16);
  }

  for (int gg = g0; gg < g1; ++gg) {
    const int ja = gg * 64, jb = ja + 32;
    const int gn = (gg + 1 < g1) ? gg + 1 : gg;
    // commit V(gg) subtiles into LDS (wave-private, in-order DS)
#pragma unroll
    for (int ii = 0; ii < 4; ++ii) {
      *reinterpret_cast<bf16x8*>(&Va[ii * 16 + srow][wchunk]) = vra[ii];
      *reinterpret_cast<bf16x8*>(&Vb[ii * 16 + srow][wchunk]) = vrb[ii];
    }
    // ---------------- subtile a ----------------
    f32x16 S = __builtin_amdgcn_mfma_f32_32x32x16_bf16(kra[0], qf[0], Z, 0, 0, 0);
    S = __builtin_amdgcn_mfma_f32_32x32x16_bf16(kra[1], qf[1], S, 0, 0, 0);
    S = __builtin_amdgcn_mfma_f32_32x32x16_bf16(kra[2], qf[2], S, 0, 0, 0);
    S = __builtin_amdgcn_mfma_f32_32x32x16_bf16(kra[3], qf[3], S, 0, 0, 0);
#pragma unroll
    for (int c = 0; c < 4; ++c)
      kra[c] = *reinterpret_cast<const bf16x8*>(kptr + (size_t)(gn * 64) * DHH + c * 16);
    if (ja + 31 > iw + HISTC) {
#pragma unroll
      for (int r = 0; r < 16; ++r) {
        int j = ja + (r & 3) + 8 * (r >> 2) + 4 * hi;
        if (j > i + HISTC) S[r] = -1e30f;
      }
    }
    {
      float u1 = fmaxf(fmaxf(S[0], S[1]), S[2]);
      float u2 = fmaxf(fmaxf(S[3], S[4]), S[5]);
      float u3 = fmaxf(fmaxf(S[6], S[7]), S[8]);
      float u4 = fmaxf(fmaxf(S[9], S[10]), S[11]);
      float u5 = fmaxf(fmaxf(S[12], S[13]), S[14]);
      float pm = fmaxf(fmaxf(fmaxf(u1, u2), u3), fmaxf(fmaxf(u4, u5), S[15]));
      if (__any(pm > m_run + 8.0f)) {
        pm = fmaxf(pm, __shfl_xor(pm, 32));
        float mn = fmaxf(m_run, pm);
        float sc = fexp2(m_run - mn);
        m_run = mn;
        lacc *= sc;
#pragma unroll
        for (int r = 0; r < 16; ++r) { O0[r] *= sc; O1[r] *= sc; }
      }
      float p[16];
#pragma unroll
      for (int r = 0; r < 16; ++r) p[r] = fexp2(S[r] - m_run);
      float s8[8];
#pragma unroll
      for (int r = 0; r < 8; ++r) s8[r] = p[r] + p[r + 8];
      lacc += ((s8[0] + s8[4]) + (s8[1] + s8[5])) + ((s8[2] + s8[6]) + (s8[3] + s8[7]));
      union { unsigned u[4]; bf16x8 v; } pf0, pf1;
      pf0.u[0] = pk2(p[0], p[1]);   pf0.u[1] = pk2(p[2], p[3]);
      pf0.u[2] = pk2(p[4], p[5]);   pf0.u[3] = pk2(p[6], p[7]);
      pf1.u[0] = pk2(p[8], p[9]);   pf1.u[1] = pk2(p[10], p[11]);
      pf1.u[2] = pk2(p[12], p[13]); pf1.u[3] = pk2(p[14], p[15]);
      bf16x8 va00 = *reinterpret_cast<const bf16x8*>(&Va[q][(hi ^ sx) * 8]);
      bf16x8 va01 = *reinterpret_cast<const bf16x8*>(&Va[q][((2 + hi) ^ sx) * 8]);
      bf16x8 va10 = *reinterpret_cast<const bf16x8*>(&Va[32 + q][(hi ^ sx) * 8]);
      bf16x8 va11 = *reinterpret_cast<const bf16x8*>(&Va[32 + q][((2 + hi) ^ sx) * 8]);
      O0 = __builtin_amdgcn_mfma_f32_32x32x16_bf16(va00, pf0.v, O0, 0, 0, 0);
      O0 = __builtin_amdgcn_mfma_f32_32x32x16_bf16(va01, pf1.v, O0, 0, 0, 0);
      O1 = __builtin_amdgcn_mfma_f32_32x32x16_bf16(va10, pf0.v, O1, 0, 0, 0);
      O1 = __builtin_amdgcn_mfma_f32_32x32x16_bf16(va11, pf1.v, O1, 0, 0, 0);
    }
    // ---------------- subtile b ----------------
    f32x16 T = __builtin_amdgcn_mfma_f32_32x32x16_bf16(krb[0], qf[0], Z, 0, 0, 0);
    T = __builtin_amdgcn_mfma_f32_32x32x16_bf16(krb[1], qf[1], T, 0, 0, 0);
    T = __builtin_amdgcn_mfma_f32_32x32x16_bf16(krb[2], qf[2], T, 0, 0, 0);
    T = __builtin_amdgcn_mfma_f32_32x32x16_bf16(krb[3], qf[3], T, 0, 0, 0);
#pragma unroll
    for (int c = 0; c < 4; ++c)
      krb[c] = *reinterpret_cast<const bf16x8*>(kptr + (size_t)(gn * 64 + 32) * DHH + c * 16);
#pragma unroll
    for (int ii = 0; ii < 4; ++ii) {
      vra[ii] = *reinterpret_cast<const bf16x8*>(vstg + (size_t)(ii * 16) * SEQ + gn * 64);
      vrb[ii] = *reinterpret_cast<const bf16x8*>(vstg + (size_t)(ii * 16) * SEQ + gn * 64 + 32);
    }
    if (jb + 31 > iw + HISTC) {
#pragma unroll
      for (int r = 0; r < 16; ++r) {
        int j = jb + (r & 3) + 8 * (r >> 2) + 4 * hi;
        if (j > i + HISTC) T[r] = -1e30f;
      }
    }
    {
      float u1 = fmaxf(fmaxf(T[0], T[1]), T[2]);
      float u2 = fmaxf(fmaxf(T[3], T[4]), T[5]);
      float u3 = fmaxf(fmaxf(T[6], T[7]), T[8]);
      float u4 = fmaxf(fmaxf(T[9], T[10]), T[11]);
      float u5 = fmaxf(fmaxf(T[12], T[13]), T[14]);
      float pm = fmaxf(fmaxf(fmaxf(u1, u2), u3), fmaxf(fmaxf(u4, u5), T[15]));
      if (__any(pm > m_run + 8.0f)) {
        pm = fmaxf(pm, __shfl_xor(pm, 32));
        float mn = fmaxf(m_run, pm);
        float sc = fexp2(m_run - mn);
        m_run = mn;
        lacc *= sc;
#pragma unroll
        for (int r = 0; r < 16; ++r) { O0[r] *= sc; O1[r] *= sc; }
      }
      float p[16];
#pragma unroll
      for (int r = 0; r < 16; ++r) p[r] = fexp2(T[r] - m_run);
      float s8[8];
#pragma unroll
      for (int r = 0; r < 8; ++r) s8[r] = p[r] + p[r + 8];
      lacc += ((s8[0] + s8[4]) + (s8[1] + s8[5])) + ((s8[2] + s8[6]) + (s8[3] + s8[7]));
      union { unsigned u[4]; bf16x8 v; } pf0, pf1;
      pf0.u[0] = pk2(p[0], p[1]);   pf0.u[1] = pk2(p[2], p[3]);
      pf0.u[2] = pk2(p[4], p[5]);   pf0.u[3] = pk2(p[6], p[7]);
      pf1.u[0] = pk2(p[8], p[9]);   pf1.u[1] = pk2(p[10], p[11]);
      pf1.u[2] = pk2(p[12], p[13]); pf1.u[3] = pk2(p[14], p[15]);
      bf16x8 vb00 = *reinterpret_cast<const bf16x8*>(&Vb[q][(hi ^ sx) * 8]);
      bf16x8 vb01 = *reinterpret_cast<const bf16x8*>(&Vb[q][((2 + hi) ^ sx) * 8]);
      bf16x8 vb10 = *reinterpret_cast<const bf16x8*>(&Vb[32 + q][(hi ^ sx) * 8]);
      bf16x8 vb11 = *reinterpret_cast<const bf16x8*>(&Vb[32 + q][((2 + hi) ^ sx) * 8]);
      O0 = __builtin_amdgcn_mfma_f32_32x32x16_bf16(vb00, pf0.v, O0, 0, 0, 0);
      O0 = __builtin_amdgcn_mfma_f32_32x32x16_bf16(vb01, pf1.v, O0, 0, 0, 0);
      O1 = __builtin_amdgcn_mfma_f32_32x32x16_bf16(vb10, pf0.v, O1, 0, 0, 0);
      O1 = __builtin_amdgcn_mfma_f32_32x32x16_bf16(vb11, pf1.v, O1, 0, 0, 0);
    }
  }
  float l_run = lacc + __shfl_xor(lacc, 32);

  // -------- merge the 4 waves' partial (O, m, l), chunked over d --------
  float (*Ow)[33] = reinterpret_cast<float(*)[33]>(smem[w]);   // overlays Va (dead)
  if (hi == 0) { Mlds[w][q] = m_run; Llds[w][q] = l_run; }
#pragma unroll
  for (int r = 0; r < 16; ++r)
    Ow[q][(r & 3) + 8 * (r >> 2) + 4 * hi] = O0[r];
  __syncthreads();
  const int mi = t >> 3, dl = (t & 7) * 4;
  float m0v = Mlds[0][mi], m1v = Mlds[1][mi], m2v = Mlds[2][mi], m3v = Mlds[3][mi];
  float mm = fmaxf(fmaxf(m0v, m1v), fmaxf(m2v, m3v));
  float sc0 = fexp2(m0v - mm), sc1 = fexp2(m1v - mm);
  float sc2 = fexp2(m2v - mm), sc3 = fexp2(m3v - mm);
  float ll = Llds[0][mi] * sc0 + Llds[1][mi] * sc1 + Llds[2][mi] * sc2 + Llds[3][mi] * sc3;
  float inv = 1.f / ll;
  __bf16* orow = aout + ((size_t)(b * LATENT) + iw + mi) * DIMC + h * DHH;
  {
    float(*O0p)[33] = reinterpret_cast<float(*)[33]>(smem[0]);
    float(*O1p)[33] = reinterpret_cast<float(*)[33]>(smem[1]);
    float(*O2p)[33] = reinterpret_cast<float(*)[33]>(smem[2]);
    float(*O3p)[33] = reinterpret_cast<float(*)[33]>(smem[3]);
    union { __bf16 hh[4]; uint2 u2; } pkv;
#pragma unroll
    for (int e = 0; e < 4; ++e) {
      float o = O0p[mi][dl + e] * sc0 + O1p[mi][dl + e] * sc1 +
                O2p[mi][dl + e] * sc2 + O3p[mi][dl + e] * sc3;
      pkv.hh[e] = (__bf16)(o * inv);
    }
    *reinterpret_cast<uint2*>(orow + dl) = pkv.u2;
  }
  __syncthreads();
#pragma unroll
  for (int r = 0; r < 16; ++r)
    Ow[q][(r & 3) + 8 * (r >> 2) + 4 * hi] = O1[r];
  __syncthreads();
  {
    float(*O0p)[33] = reinterpret_cast<float(*)[33]>(smem[0]);
    float(*O1p)[33] = reinterpret_cast<float(*)[33]>(smem[1]);
    float(*O2p)[33] = reinterpret_cast<float(*)[33]>(smem[2]);
    float(*O3p)[33] = reinterpret_cast<float(*)[33]>(smem[3]);
    union { __bf16 hh[4]; uint2 u2; } pkv;
#pragma unroll
    for (int e = 0; e < 4; ++e) {
      float o = O0p[mi][dl + e] * sc0 + O1p[mi][dl + e] * sc1 +
                O2p[mi][dl + e] * sc2 + O3p[mi][dl + e] * sc3;
      pkv.hh[e] = (__bf16)(o * inv);
    }
    *reinterpret_cast<uint2*>(orow + 32 + dl) = pkv.u2;
  }
}

// ---------------- host launcher ----------------
extern "C" void kernel_launch(void* const* d_in, const int* in_sizes, int n_in,
                              void* d_out, int out_size, void* d_ws, size_t ws_size,
                              hipStream_t stream) {
  const float* x = (const float*)d_in[0];
  const float* Wq = (const float*)d_in[1];
  const float* Wkv = (const float*)d_in[2];
  const float* Wo = (const float*)d_in[3];
  const float* bo = (const float*)d_in[4];
  const float* gamma = (const float*)d_in[5];
  const float* beta = (const float*)d_in[6];

  char* ws = (char*)d_ws;
  size_t o = 0;
  __bf16* x16 = (__bf16*)(ws + o);  o += (size_t)BATCH * SEQ * DIMC * 2;
  __bf16* wq16 = (__bf16*)(ws + o); o += (size_t)DIMC * DIMC * 2;
  __bf16* wkv16 = (__bf16*)(ws + o); o += (size_t)DIMC * DIMC * 2;
  __bf16* wo16 = (__bf16*)(ws + o); o += (size_t)DIMC * DIMC * 2;
  float2* cstab = (float2*)(ws + o); o += (size_t)SEQ * 32 * 8;
  __bf16* kvn = (__bf16*)(ws + o);  o += (size_t)BATCH * HEADS * SEQ * DHH * 2;
  __bf16* kvnT = (__bf16*)(ws + o); o += (size_t)BATCH * HEADS * SEQ * DHH * 2;
  __bf16* qb = (__bf16*)(ws + o);   o += (size_t)BATCH * HEADS * LATENT * DHH * 2;
  __bf16* aout = (__bf16*)(ws + o); o += (size_t)BATCH * LATENT * DIMC * 2;

  k_convert<<<2048, 256, 0, stream>>>(x, x16, BATCH * SEQ * DIMC);
  k_convert3<<<1536, 256, 0, stream>>>(Wq, Wkv, Wo, wq16, wkv16, wo16);
  k_cstab<<<512, 256, 0, stream>>>(cstab);
  k_gemmqkv<<<dim3(8, 80), 256, 0, stream>>>(x16, wkv16, wq16, kvn, kvnT, qb, gamma, beta, cstab);
  k_flash7<<<1024, 256, 0, stream>>>(qb, kvn, kvnT, aout);
  k_gemm<0, 1><<<dim3(8, 16), 256, 0, stream>>>(aout, wo16, (float*)d_out, bo, 2048, 1024, 1024);
}

// Round 10
// 168.114 us; speedup vs baseline: 1.2569x; 1.0177x over previous
//
#include <hip/hip_runtime.h>
#include <hip/hip_bf16.h>
#include <cstdint>

#define DIMC 1024
#define HEADS 16
#define DHH 64
#define SEQ 4096
#define LATENT 1024
#define HISTC 3072
#define BATCH 2

typedef __attribute__((ext_vector_type(8))) __bf16 bf16x8;
typedef __attribute__((ext_vector_type(4))) float f32x4;
typedef __attribute__((ext_vector_type(16))) float f32x16;

// ---------------- fused prep: x->bf16, 3 weights->bf16, RoPE cos/sin table ----
__global__ void k_prep(const float* __restrict__ x, const float* __restrict__ Wq,
                       const float* __restrict__ Wkv, const float* __restrict__ Wo,
                       __bf16* __restrict__ x16, __bf16* __restrict__ wq16,
                       __bf16* __restrict__ wkv16, __bf16* __restrict__ wo16,
                       float2* __restrict__ cs) {
  int bidx = blockIdx.x;
  if (bidx < 2048) {
    // x: 8.4M floats = 2.09M float4; 2048x256 threads x 4 chunks
    int base = bidx * 256 + threadIdx.x;
#pragma unroll
    for (int k = 0; k < 4; ++k) {
      int i = base + k * 524288;
      float4 v = reinterpret_cast<const float4*>(x)[i];
      union { __bf16 h[4]; uint64_t u; } p;
      p.h[0] = (__bf16)v.x; p.h[1] = (__bf16)v.y;
      p.h[2] = (__bf16)v.z; p.h[3] = (__bf16)v.w;
      reinterpret_cast<uint64_t*>(x16)[i] = p.u;
    }
  } else if (bidx < 3584) {
    int id = bidx - 2048;
    const float* src; __bf16* dst;
    if (id < 512) { src = Wq; dst = wq16; }
    else if (id < 1024) { src = Wkv; dst = wkv16; id -= 512; }
    else { src = Wo; dst = wo16; id -= 1024; }
#pragma unroll
    for (int k = 0; k < 2; ++k) {
      int idx = id * 512 + k * 256 + threadIdx.x;
      float4 v = reinterpret_cast<const float4*>(src)[idx];
      union { __bf16 h[4]; uint64_t u; } p;
      p.h[0] = (__bf16)v.x; p.h[1] = (__bf16)v.y;
      p.h[2] = (__bf16)v.z; p.h[3] = (__bf16)v.w;
      reinterpret_cast<uint64_t*>(dst)[idx] = p.u;
    }
  } else {
    int idx = (bidx - 3584) * 256 + threadIdx.x;   // 4096*32 entries
    int pos = idx >> 5, f = idx & 31;
    float invf = exp2f(-(float)f * 0.41524101186f);  // log2(10000)/32
    float s, c;
    sincosf((float)pos * invf, &s, &c);
    cs[idx] = make_float2(c, s);
  }
}

// ---------------- async global->LDS 16B ----------------
__device__ __forceinline__ void gload16(void* lds, const void* g) {
  __builtin_amdgcn_global_load_lds(
      (const __attribute__((address_space(1))) unsigned int*)g,
      (__attribute__((address_space(3))) unsigned int*)lds, 16, 0, 0);
}

// ---------------- plain GEMM (o-proj): C = A @ Bw^T + bias ----
// 1D grid, by = bid % mblocks -> blocks sharing an A-panel land on one XCD (T1).
template<int BIAS>
__launch_bounds__(256)
__global__ void k_gemm(const __bf16* __restrict__ A, const __bf16* __restrict__ Bw,
                       float* __restrict__ C, const float* __restrict__ bias,
                       int M, int N, int K) {
  __shared__ __align__(16) char lds[16384];
  const int t = threadIdx.x;
  const int l = t & 63, w = t >> 6;
  const int wr = w >> 1, wc = w & 1;
  const int mblocks = M >> 7;
  const int m0 = (blockIdx.x % mblocks) * 128, n0 = (blockIdx.x / mblocks) * 128;
  const int lrow = l & 15, lk = l >> 4;
  f32x4 acc[4][4] = {};

  for (int k0 = 0; k0 < K; k0 += 32) {
    if (k0) __syncthreads();
#pragma unroll
    for (int i = 0; i < 2; ++i) {
      int c = i * 256 + t;
      int row = c >> 2, kc = c & 3;
      gload16(lds + c * 16, A + (size_t)(m0 + row) * K + k0 + kc * 8);
      gload16(lds + 8192 + c * 16, Bw + (size_t)(n0 + row) * K + k0 + kc * 8);
    }
    __syncthreads();
    bf16x8 af[4], bfr[4];
#pragma unroll
    for (int m = 0; m < 4; ++m)
      af[m] = *reinterpret_cast<const bf16x8*>(lds + (wr * 64 + m * 16 + lrow) * 64 + lk * 16);
#pragma unroll
    for (int n = 0; n < 4; ++n)
      bfr[n] = *reinterpret_cast<const bf16x8*>(lds + 8192 + (wc * 64 + n * 16 + lrow) * 64 + lk * 16);
#pragma unroll
    for (int m = 0; m < 4; ++m)
#pragma unroll
      for (int n = 0; n < 4; ++n)
        acc[m][n] = __builtin_amdgcn_mfma_f32_16x16x32_bf16(af[m], bfr[n], acc[m][n], 0, 0, 0);
  }

#pragma unroll
  for (int m = 0; m < 4; ++m)
#pragma unroll
    for (int n = 0; n < 4; ++n)
#pragma unroll
      for (int r = 0; r < 4; ++r) {
        int row = m0 + wr * 64 + m * 16 + (l >> 4) * 4 + r;
        int col = n0 + wc * 64 + n * 16 + (l & 15);
        float v = acc[m][n][r];
        if (BIAS) v += bias[col];
        C[(size_t)row * N + col] = v;
      }
}

// ---------------- fused QKV GEMM: kv-proj(+RoPE+LN) and q-proj(+RoPE+scale) ----
// 1D grid 640: by = bid % 80, bx = bid / 80 -> the 8 n-blocks sharing one
// A-panel (256KB of x16) land on ONE XCD's L2 instead of 8 (T1).
__launch_bounds__(256)
__global__ void k_gemmqkv(const __bf16* __restrict__ x16,
                          const __bf16* __restrict__ wkv16,
                          const __bf16* __restrict__ wq16,
                          __bf16* __restrict__ kvn, __bf16* __restrict__ kvnT,
                          __bf16* __restrict__ qb,
                          const float* __restrict__ gamma,
                          const float* __restrict__ beta,
                          const float2* __restrict__ cstab) {
  __shared__ __align__(16) char lds[16384];
  const int t = threadIdx.x, l = t & 63, w = t >> 6;
  const int wr = w >> 1, wc = w & 1;
  const int by = blockIdx.x % 80;
  const bool isq = by >= 64;
  const int m0 = (isq ? (by - 64) : by) * 128;
  const int n0 = (blockIdx.x / 80) * 128;
  const __bf16* Bw = isq ? wq16 : wkv16;
  const int lrow = l & 15, lk = l >> 4;
  f32x4 acc[4][4] = {};

  for (int k0 = 0; k0 < 1024; k0 += 32) {
    if (k0) __syncthreads();
#pragma unroll
    for (int i = 0; i < 2; ++i) {
      int c = i * 256 + t;
      int row = c >> 2, kc = c & 3;
      int mi = m0 + row;
      if (isq) mi += HISTC + (mi >> 10) * HISTC;
      gload16(lds + c * 16, x16 + (size_t)mi * 1024 + k0 + kc * 8);
      gload16(lds + 8192 + c * 16, Bw + (size_t)(n0 + row) * 1024 + k0 + kc * 8);
    }
    __syncthreads();
    bf16x8 af[4], bfr[4];
#pragma unroll
    for (int m = 0; m < 4; ++m)
      af[m] = *reinterpret_cast<const bf16x8*>(lds + (wr * 64 + m * 16 + lrow) * 64 + lk * 16);
#pragma unroll
    for (int n = 0; n < 4; ++n)
      bfr[n] = *reinterpret_cast<const bf16x8*>(lds + 8192 + (wc * 64 + n * 16 + lrow) * 64 + lk * 16);
#pragma unroll
    for (int m = 0; m < 4; ++m)
#pragma unroll
      for (int n = 0; n < 4; ++n)
        acc[m][n] = __builtin_amdgcn_mfma_f32_16x16x32_bf16(af[m], bfr[n], acc[m][n], 0, 0, 0);
  }

  // ---- RoPE in place via table (pairs (0,2) and (1,3) share one lane) ----
#pragma unroll
  for (int m = 0; m < 4; ++m)
#pragma unroll
    for (int r = 0; r < 4; ++r) {
      int rl = wr * 64 + m * 16 + lk * 4 + r;
      int pos = isq ? (HISTC + ((m0 + rl) & 1023)) : ((m0 + rl) & 4095);
      float2 cs0 = cstab[pos * 32 + lrow];
      float2 cs1 = cstab[pos * 32 + 16 + lrow];
      float a0 = acc[m][0][r], a2 = acc[m][2][r];
      acc[m][0][r] = a0 * cs0.x - a2 * cs0.y;
      acc[m][2][r] = a2 * cs0.x + a0 * cs0.y;
      float a1 = acc[m][1][r], a3 = acc[m][3][r];
      acc[m][1][r] = a1 * cs1.x - a3 * cs1.y;
      acc[m][3][r] = a3 * cs1.x + a1 * cs1.y;
    }

  const int h = (n0 + wc * 64) >> 6;
  if (!isq) {
    // ---- per-head LayerNorm over the 64 cols (16-lane reduction) ----
    float g4[4], b4[4];
#pragma unroll
    for (int n = 0; n < 4; ++n) { g4[n] = gamma[n * 16 + lrow]; b4[n] = beta[n * 16 + lrow]; }
#pragma unroll
    for (int m = 0; m < 4; ++m)
#pragma unroll
      for (int r = 0; r < 4; ++r) {
        float s1 = acc[m][0][r] + acc[m][1][r] + acc[m][2][r] + acc[m][3][r];
        float s2 = acc[m][0][r] * acc[m][0][r] + acc[m][1][r] * acc[m][1][r] +
                   acc[m][2][r] * acc[m][2][r] + acc[m][3][r] * acc[m][3][r];
#pragma unroll
        for (int mk = 1; mk < 16; mk <<= 1) {
          s1 += __shfl_xor(s1, mk);
          s2 += __shfl_xor(s2, mk);
        }
        float mu = s1 * 0.015625f;
        float var = s2 * 0.015625f - mu * mu;
        float inv = rsqrtf(var + 1e-5f);
#pragma unroll
        for (int n = 0; n < 4; ++n)
          acc[m][n][r] = (acc[m][n][r] - mu) * inv * g4[n] + b4[n];
      }
    const size_t hb = (size_t)((m0 >> 12) * HEADS + h);
    // kvn [b,h,pos,d]
#pragma unroll
    for (int m = 0; m < 4; ++m)
#pragma unroll
      for (int r = 0; r < 4; ++r) {
        int pos = (m0 + wr * 64 + m * 16 + lk * 4 + r) & 4095;
#pragma unroll
        for (int n = 0; n < 4; ++n)
          kvn[(hb * SEQ + pos) * DHH + n * 16 + lrow] = (__bf16)acc[m][n][r];
      }
    // kvnT [b,h,d,sigma(pos)] : r-quads stay contiguous under sigma (bits 2,3 swap)
#pragma unroll
    for (int m = 0; m < 4; ++m) {
      int pos0 = (m0 + wr * 64 + m * 16 + lk * 4) & 4095;
      int sp = (pos0 & ~12) | ((pos0 & 4) << 1) | ((pos0 & 8) >> 1);
#pragma unroll
      for (int n = 0; n < 4; ++n) {
        union { __bf16 hh[4]; uint64_t u; } pk;
#pragma unroll
        for (int r = 0; r < 4; ++r) pk.hh[r] = (__bf16)acc[m][n][r];
        *reinterpret_cast<uint64_t*>(kvnT + (hb * DHH + n * 16 + lrow) * SEQ + sp) = pk.u;
      }
    }
  } else {
    // ---- q: scale by DH^-0.5 * log2(e), write qb [b,h,i,d] ----
    const size_t hb = (size_t)((m0 >> 10) * HEADS + h);
#pragma unroll
    for (int m = 0; m < 4; ++m)
#pragma unroll
      for (int r = 0; r < 4; ++r) {
        int qi = (m0 + wr * 64 + m * 16 + lk * 4 + r) & 1023;
#pragma unroll
        for (int n = 0; n < 4; ++n)
          qb[(hb * LATENT + qi) * DHH + n * 16 + lrow] =
              (__bf16)(acc[m][n][r] * 0.18033688011112042f);
      }
  }
}

// ---------------- helpers for flash ----------------
__device__ __forceinline__ float fexp2(float x) {
#if __has_builtin(__builtin_amdgcn_exp2f)
  return __builtin_amdgcn_exp2f(x);
#else
  return exp2f(x);
#endif
}

__device__ __forceinline__ unsigned pk2(float a, float b) {
  union { __bf16 h[2]; unsigned u; } x;
  x.h[0] = (__bf16)a; x.h[1] = (__bf16)b;
  return x.u;
}

// ---------------- flash attention v7b (verified 88us, unchanged) ----------------
__launch_bounds__(256)
__global__ void k_flash7(const __bf16* __restrict__ qb, const __bf16* __restrict__ kvn,
                         const __bf16* __restrict__ kvnT, __bf16* __restrict__ aout) {
  const int bid = blockIdx.x;
  const int g = bid >> 8;
  const int bh = (bid & 7) + 8 * g;
  int itile = (bid >> 3) & 31;
  if (g & 1) itile = 31 - itile;                 // balance work across CUs
  const int h = bh & 15, b = bh >> 4;
  const int t = threadIdx.x, l = t & 63, w = t >> 6;
  const int q = l & 31, hi = l >> 5;
  const int iw = itile * 32;
  const int i = iw + q;
  const __bf16* qbase = qb + ((size_t)(b * HEADS + h) * LATENT + iw) * DHH;
  const __bf16* kbase = kvn + (size_t)(b * HEADS + h) * SEQ * DHH;
  const __bf16* vbase = kvnT + (size_t)(b * HEADS + h) * DHH * SEQ;

  __shared__ __align__(16) char smem[4][8192];
  __shared__ float Mlds[4][32];
  __shared__ float Llds[4][32];
  __bf16 (*Va)[32] = reinterpret_cast<__bf16(*)[32]>(smem[w]);
  __bf16 (*Vb)[32] = reinterpret_cast<__bf16(*)[32]>(smem[w] + 4096);

  bf16x8 qf[4];
#pragma unroll
  for (int c = 0; c < 4; ++c)
    qf[c] = *reinterpret_cast<const bf16x8*>(qbase + (size_t)q * DHH + c * 16 + hi * 8);

  const f32x16 Z = {};
  f32x16 O0 = {}, O1 = {};
  float m_run = -INFINITY, lacc = 0.f;

  const int nt64 = (itile + 98) >> 1;
  const int g0 = (nt64 * w) >> 2, g1 = (nt64 * (w + 1)) >> 2;

  const int srow = l >> 2, scol = l & 3;
  const int wchunk = (scol ^ (srow & 3)) * 8;
  const int sx = q & 3;

  const __bf16* vstg = vbase + (size_t)srow * SEQ + scol * 8;
  const __bf16* kptr = kbase + (size_t)q * DHH + hi * 8;

  bf16x8 vra[4], vrb[4], kra[4], krb[4];
#pragma unroll
  for (int ii = 0; ii < 4; ++ii) {
    vra[ii] = *reinterpret_cast<const bf16x8*>(vstg + (size_t)(ii * 16) * SEQ + g0 * 64);
    vrb[ii] = *reinterpret_cast<const bf16x8*>(vstg + (size_t)(ii * 16) * SEQ + g0 * 64 + 32);
  }
#pragma unroll
  for (int c = 0; c < 4; ++c) {
    kra[c] = *reinterpret_cast<const bf16x8*>(kptr + (size_t)(g0 * 64) * DHH + c * 16);
    krb[c] = *reinterpret_cast<const bf16x8*>(kptr + (size_t)(g0 * 64 + 32) * DHH + c * 16);
  }

  for (int gg = g0; gg < g1; ++gg) {
    const int ja = gg * 64, jb = ja + 32;
    const int gn = (gg + 1 < g1) ? gg + 1 : gg;
#pragma unroll
    for (int ii = 0; ii < 4; ++ii) {
      *reinterpret_cast<bf16x8*>(&Va[ii * 16 + srow][wchunk]) = vra[ii];
      *reinterpret_cast<bf16x8*>(&Vb[ii * 16 + srow][wchunk]) = vrb[ii];
    }
    // ---------------- subtile a ----------------
    f32x16 S = __builtin_amdgcn_mfma_f32_32x32x16_bf16(kra[0], qf[0], Z, 0, 0, 0);
    S = __builtin_amdgcn_mfma_f32_32x32x16_bf16(kra[1], qf[1], S, 0, 0, 0);
    S = __builtin_amdgcn_mfma_f32_32x32x16_bf16(kra[2], qf[2], S, 0, 0, 0);
    S = __builtin_amdgcn_mfma_f32_32x32x16_bf16(kra[3], qf[3], S, 0, 0, 0);
#pragma unroll
    for (int c = 0; c < 4; ++c)
      kra[c] = *reinterpret_cast<const bf16x8*>(kptr + (size_t)(gn * 64) * DHH + c * 16);
    if (ja + 31 > iw + HISTC) {
#pragma unroll
      for (int r = 0; r < 16; ++r) {
        int j = ja + (r & 3) + 8 * (r >> 2) + 4 * hi;
        if (j > i + HISTC) S[r] = -1e30f;
      }
    }
    {
      float u1 = fmaxf(fmaxf(S[0], S[1]), S[2]);
      float u2 = fmaxf(fmaxf(S[3], S[4]), S[5]);
      float u3 = fmaxf(fmaxf(S[6], S[7]), S[8]);
      float u4 = fmaxf(fmaxf(S[9], S[10]), S[11]);
      float u5 = fmaxf(fmaxf(S[12], S[13]), S[14]);
      float pm = fmaxf(fmaxf(fmaxf(u1, u2), u3), fmaxf(fmaxf(u4, u5), S[15]));
      if (__any(pm > m_run + 8.0f)) {
        pm = fmaxf(pm, __shfl_xor(pm, 32));
        float mn = fmaxf(m_run, pm);
        float sc = fexp2(m_run - mn);
        m_run = mn;
        lacc *= sc;
#pragma unroll
        for (int r = 0; r < 16; ++r) { O0[r] *= sc; O1[r] *= sc; }
      }
      float p[16];
#pragma unroll
      for (int r = 0; r < 16; ++r) p[r] = fexp2(S[r] - m_run);
      float s8[8];
#pragma unroll
      for (int r = 0; r < 8; ++r) s8[r] = p[r] + p[r + 8];
      lacc += ((s8[0] + s8[4]) + (s8[1] + s8[5])) + ((s8[2] + s8[6]) + (s8[3] + s8[7]));
      union { unsigned u[4]; bf16x8 v; } pf0, pf1;
      pf0.u[0] = pk2(p[0], p[1]);   pf0.u[1] = pk2(p[2], p[3]);
      pf0.u[2] = pk2(p[4], p[5]);   pf0.u[3] = pk2(p[6], p[7]);
      pf1.u[0] = pk2(p[8], p[9]);   pf1.u[1] = pk2(p[10], p[11]);
      pf1.u[2] = pk2(p[12], p[13]); pf1.u[3] = pk2(p[14], p[15]);
      bf16x8 va00 = *reinterpret_cast<const bf16x8*>(&Va[q][(hi ^ sx) * 8]);
      bf16x8 va01 = *reinterpret_cast<const bf16x8*>(&Va[q][((2 + hi) ^ sx) * 8]);
      bf16x8 va10 = *reinterpret_cast<const bf16x8*>(&Va[32 + q][(hi ^ sx) * 8]);
      bf16x8 va11 = *reinterpret_cast<const bf16x8*>(&Va[32 + q][((2 + hi) ^ sx) * 8]);
      O0 = __builtin_amdgcn_mfma_f32_32x32x16_bf16(va00, pf0.v, O0, 0, 0, 0);
      O0 = __builtin_amdgcn_mfma_f32_32x32x16_bf16(va01, pf1.v, O0, 0, 0, 0);
      O1 = __builtin_amdgcn_mfma_f32_32x32x16_bf16(va10, pf0.v, O1, 0, 0, 0);
      O1 = __builtin_amdgcn_mfma_f32_32x32x16_bf16(va11, pf1.v, O1, 0, 0, 0);
    }
    // ---------------- subtile b ----------------
    f32x16 T = __builtin_amdgcn_mfma_f32_32x32x16_bf16(krb[0], qf[0], Z, 0, 0, 0);
    T = __builtin_amdgcn_mfma_f32_32x32x16_bf16(krb[1], qf[1], T, 0, 0, 0);
    T = __builtin_amdgcn_mfma_f32_32x32x16_bf16(krb[2], qf[2], T, 0, 0, 0);
    T = __builtin_amdgcn_mfma_f32_32x32x16_bf16(krb[3], qf[3], T, 0, 0, 0);
#pragma unroll
    for (int c = 0; c < 4; ++c)
      krb[c] = *reinterpret_cast<const bf16x8*>(kptr + (size_t)(gn * 64 + 32) * DHH + c * 16);
#pragma unroll
    for (int ii = 0; ii < 4; ++ii) {
      vra[ii] = *reinterpret_cast<const bf16x8*>(vstg + (size_t)(ii * 16) * SEQ + gn * 64);
      vrb[ii] = *reinterpret_cast<const bf16x8*>(vstg + (size_t)(ii * 16) * SEQ + gn * 64 + 32);
    }
    if (jb + 31 > iw + HISTC) {
#pragma unroll
      for (int r = 0; r < 16; ++r) {
        int j = jb + (r & 3) + 8 * (r >> 2) + 4 * hi;
        if (j > i + HISTC) T[r] = -1e30f;
      }
    }
    {
      float u1 = fmaxf(fmaxf(T[0], T[1]), T[2]);
      float u2 = fmaxf(fmaxf(T[3], T[4]), T[5]);
      float u3 = fmaxf(fmaxf(T[6], T[7]), T[8]);
      float u4 = fmaxf(fmaxf(T[9], T[10]), T[11]);
      float u5 = fmaxf(fmaxf(T[12], T[13]), T[14]);
      float pm = fmaxf(fmaxf(fmaxf(u1, u2), u3), fmaxf(fmaxf(u4, u5), T[15]));
      if (__any(pm > m_run + 8.0f)) {
        pm = fmaxf(pm, __shfl_xor(pm, 32));
        float mn = fmaxf(m_run, pm);
        float sc = fexp2(m_run - mn);
        m_run = mn;
        lacc *= sc;
#pragma unroll
        for (int r = 0; r < 16; ++r) { O0[r] *= sc; O1[r] *= sc; }
      }
      float p[16];
#pragma unroll
      for (int r = 0; r < 16; ++r) p[r] = fexp2(T[r] - m_run);
      float s8[8];
#pragma unroll
      for (int r = 0; r < 8; ++r) s8[r] = p[r] + p[r + 8];
      lacc += ((s8[0] + s8[4]) + (s8[1] + s8[5])) + ((s8[2] + s8[6]) + (s8[3] + s8[7]));
      union { unsigned u[4]; bf16x8 v; } pf0, pf1;
      pf0.u[0] = pk2(p[0], p[1]);   pf0.u[1] = pk2(p[2], p[3]);
      pf0.u[2] = pk2(p[4], p[5]);   pf0.u[3] = pk2(p[6], p[7]);
      pf1.u[0] = pk2(p[8], p[9]);   pf1.u[1] = pk2(p[10], p[11]);
      pf1.u[2] = pk2(p[12], p[13]); pf1.u[3] = pk2(p[14], p[15]);
      bf16x8 vb00 = *reinterpret_cast<const bf16x8*>(&Vb[q][(hi ^ sx) * 8]);
      bf16x8 vb01 = *reinterpret_cast<const bf16x8*>(&Vb[q][((2 + hi) ^ sx) * 8]);
      bf16x8 vb10 = *reinterpret_cast<const bf16x8*>(&Vb[32 + q][(hi ^ sx) * 8]);
      bf16x8 vb11 = *reinterpret_cast<const bf16x8*>(&Vb[32 + q][((2 + hi) ^ sx) * 8]);
      O0 = __builtin_amdgcn_mfma_f32_32x32x16_bf16(vb00, pf0.v, O0, 0, 0, 0);
      O0 = __builtin_amdgcn_mfma_f32_32x32x16_bf16(vb01, pf1.v, O0, 0, 0, 0);
      O1 = __builtin_amdgcn_mfma_f32_32x32x16_bf16(vb10, pf0.v, O1, 0, 0, 0);
      O1 = __builtin_amdgcn_mfma_f32_32x32x16_bf16(vb11, pf1.v, O1, 0, 0, 0);
    }
  }
  float l_run = lacc + __shfl_xor(lacc, 32);

  // -------- merge the 4 waves' partial (O, m, l), chunked over d --------
  float (*Ow)[33] = reinterpret_cast<float(*)[33]>(smem[w]);
  if (hi == 0) { Mlds[w][q] = m_run; Llds[w][q] = l_run; }
#pragma unroll
  for (int r = 0; r < 16; ++r)
    Ow[q][(r & 3) + 8 * (r >> 2) + 4 * hi] = O0[r];
  __syncthreads();
  const int mi = t >> 3, dl = (t & 7) * 4;
  float m0v = Mlds[0][mi], m1v = Mlds[1][mi], m2v = Mlds[2][mi], m3v = Mlds[3][mi];
  float mm = fmaxf(fmaxf(m0v, m1v), fmaxf(m2v, m3v));
  float sc0 = fexp2(m0v - mm), sc1 = fexp2(m1v - mm);
  float sc2 = fexp2(m2v - mm), sc3 = fexp2(m3v - mm);
  float ll = Llds[0][mi] * sc0 + Llds[1][mi] * sc1 + Llds[2][mi] * sc2 + Llds[3][mi] * sc3;
  float inv = 1.f / ll;
  __bf16* orow = aout + ((size_t)(b * LATENT) + iw + mi) * DIMC + h * DHH;
  {
    float(*O0p)[33] = reinterpret_cast<float(*)[33]>(smem[0]);
    float(*O1p)[33] = reinterpret_cast<float(*)[33]>(smem[1]);
    float(*O2p)[33] = reinterpret_cast<float(*)[33]>(smem[2]);
    float(*O3p)[33] = reinterpret_cast<float(*)[33]>(smem[3]);
    union { __bf16 hh[4]; uint2 u2; } pkv;
#pragma unroll
    for (int e = 0; e < 4; ++e) {
      float o = O0p[mi][dl + e] * sc0 + O1p[mi][dl + e] * sc1 +
                O2p[mi][dl + e] * sc2 + O3p[mi][dl + e] * sc3;
      pkv.hh[e] = (__bf16)(o * inv);
    }
    *reinterpret_cast<uint2*>(orow + dl) = pkv.u2;
  }
  __syncthreads();
#pragma unroll
  for (int r = 0; r < 16; ++r)
    Ow[q][(r & 3) + 8 * (r >> 2) + 4 * hi] = O1[r];
  __syncthreads();
  {
    float(*O0p)[33] = reinterpret_cast<float(*)[33]>(smem[0]);
    float(*O1p)[33] = reinterpret_cast<float(*)[33]>(smem[1]);
    float(*O2p)[33] = reinterpret_cast<float(*)[33]>(smem[2]);
    float(*O3p)[33] = reinterpret_cast<float(*)[33]>(smem[3]);
    union { __bf16 hh[4]; uint2 u2; } pkv;
#pragma unroll
    for (int e = 0; e < 4; ++e) {
      float o = O0p[mi][dl + e] * sc0 + O1p[mi][dl + e] * sc1 +
                O2p[mi][dl + e] * sc2 + O3p[mi][dl + e] * sc3;
      pkv.hh[e] = (__bf16)(o * inv);
    }
    *reinterpret_cast<uint2*>(orow + 32 + dl) = pkv.u2;
  }
}

// ---------------- host launcher ----------------
extern "C" void kernel_launch(void* const* d_in, const int* in_sizes, int n_in,
                              void* d_out, int out_size, void* d_ws, size_t ws_size,
                              hipStream_t stream) {
  const float* x = (const float*)d_in[0];
  const float* Wq = (const float*)d_in[1];
  const float* Wkv = (const float*)d_in[2];
  const float* Wo = (const float*)d_in[3];
  const float* bo = (const float*)d_in[4];
  const float* gamma = (const float*)d_in[5];
  const float* beta = (const float*)d_in[6];

  char* ws = (char*)d_ws;
  size_t o = 0;
  __bf16* x16 = (__bf16*)(ws + o);  o += (size_t)BATCH * SEQ * DIMC * 2;
  __bf16* wq16 = (__bf16*)(ws + o); o += (size_t)DIMC * DIMC * 2;
  __bf16* wkv16 = (__bf16*)(ws + o); o += (size_t)DIMC * DIMC * 2;
  __bf16* wo16 = (__bf16*)(ws + o); o += (size_t)DIMC * DIMC * 2;
  float2* cstab = (float2*)(ws + o); o += (size_t)SEQ * 32 * 8;
  __bf16* kvn = (__bf16*)(ws + o);  o += (size_t)BATCH * HEADS * SEQ * DHH * 2;
  __bf16* kvnT = (__bf16*)(ws + o); o += (size_t)BATCH * HEADS * SEQ * DHH * 2;
  __bf16* qb = (__bf16*)(ws + o);   o += (size_t)BATCH * HEADS * LATENT * DHH * 2;
  __bf16* aout = (__bf16*)(ws + o); o += (size_t)BATCH * LATENT * DIMC * 2;

  k_prep<<<4096, 256, 0, stream>>>(x, Wq, Wkv, Wo, x16, wq16, wkv16, wo16, cstab);
  k_gemmqkv<<<640, 256, 0, stream>>>(x16, wkv16, wq16, kvn, kvnT, qb, gamma, beta, cstab);
  k_flash7<<<1024, 256, 0, stream>>>(qb, kvn, kvnT, aout);
  k_gemm<1><<<128, 256, 0, stream>>>(aout, wo16, (float*)d_out, bo, 2048, 1024, 1024);
}